// Round 3
// baseline (643.366 us; speedup 1.0000x reference)
//
#include <hip/hip_runtime.h>
#include <hip/hip_bf16.h>
#include <math.h>

using short8   = __attribute__((ext_vector_type(8))) short;
using floatx4  = __attribute__((ext_vector_type(4))) float;
using floatx16 = __attribute__((ext_vector_type(16))) float;

#define B_N  32
#define S_N  1026
#define R_N  256
#define H_N  1024
#define NH_N 16
#define HD_N 64
#define SP_N 1088          // padded S for V^T rows: 17 * 64, pad cols zeroed once
#define KTILES 17          // SP_N / 64

__device__ __forceinline__ float bf2f(__hip_bfloat16 x) { return __bfloat162float(x); }
__device__ __forceinline__ __hip_bfloat16 f2bf(float x) { return __float2bfloat16(x); }

__device__ __forceinline__ float fast_exp2(float x) {
#if __has_builtin(__builtin_amdgcn_exp2f)
    return __builtin_amdgcn_exp2f(x);
#else
    return exp2f(x);
#endif
}

// pack two f32 -> one u32 of two bf16 (RNE), single instruction
__device__ __forceinline__ unsigned cvtpk(float lo, float hi_) {
    unsigned r;
    asm("v_cvt_pk_bf16_f32 %0, %1, %2" : "=v"(r) : "v"(lo), "v"(hi_));
    return r;
}

// async global->LDS, 16B per lane; LDS dest = uniform base + lane*16
__device__ __forceinline__ void gl_lds16(const void* g, void* l) {
    __builtin_amdgcn_global_load_lds(
        (const __attribute__((address_space(1))) unsigned int*)g,
        (__attribute__((address_space(3))) unsigned int*)l, 16, 0, 0);
}

// convert 8 fp32 (two float4) -> short8 of bf16
__device__ __forceinline__ short8 cvt8(const float* __restrict__ p) {
    floatx4 a = *(const floatx4*)p;
    floatx4 b = *(const floatx4*)(p + 4);
    short8 o;
    __hip_bfloat16* op = (__hip_bfloat16*)&o;
    op[0] = f2bf(a[0]); op[1] = f2bf(a[1]); op[2] = f2bf(a[2]); op[3] = f2bf(a[3]);
    op[4] = f2bf(b[0]); op[5] = f2bf(b[1]); op[6] = f2bf(b[2]); op[7] = f2bf(b[3]);
    return o;
}

// ---------------- LDS-tiled transpose + downcast for Wq/Wk/Wv (one launch, z-select) ---
__global__ __launch_bounds__(256) void transpose3_kernel(
    const float* __restrict__ a, const float* __restrict__ b, const float* __restrict__ c,
    __hip_bfloat16* __restrict__ oa, __hip_bfloat16* __restrict__ ob,
    __hip_bfloat16* __restrict__ oc, int K, int N) {
    __shared__ __hip_bfloat16 t[32][33];
    const float* in = (blockIdx.z == 0) ? a : (blockIdx.z == 1) ? b : c;
    __hip_bfloat16* out = (blockIdx.z == 0) ? oa : (blockIdx.z == 1) ? ob : oc;
    const int k0 = blockIdx.x * 32, n0 = blockIdx.y * 32;
    const int tx = threadIdx.x & 31, ty = threadIdx.x >> 5;   // 32 x 8
#pragma unroll
    for (int j = 0; j < 32; j += 8)
        t[ty + j][tx] = f2bf(in[(size_t)(k0 + ty + j) * N + n0 + tx]);
    __syncthreads();
#pragma unroll
    for (int j = 0; j < 32; j += 8)
        out[(size_t)(n0 + ty + j) * K + k0 + tx] = t[tx][ty + j];
}

__global__ __launch_bounds__(256) void transpose_kernel(const float* __restrict__ in,
                                                        __hip_bfloat16* __restrict__ out,
                                                        int K, int N) {
    __shared__ __hip_bfloat16 t[32][33];
    const int k0 = blockIdx.x * 32, n0 = blockIdx.y * 32;
    const int tx = threadIdx.x & 31, ty = threadIdx.x >> 5;
#pragma unroll
    for (int j = 0; j < 32; j += 8)
        t[ty + j][tx] = f2bf(in[(size_t)(k0 + ty + j) * N + n0 + tx]);
    __syncthreads();
#pragma unroll
    for (int j = 0; j < 32; j += 8)
        out[(size_t)(n0 + ty + j) * K + k0 + tx] = t[tx][ty + j];
}

// ---------------- fused fp32 -> bf16 convert for q/k/v_low (one launch) ----------------
__global__ __launch_bounds__(256) void cvtx_kernel(
    const float* __restrict__ q, const float* __restrict__ k, const float* __restrict__ v,
    __hip_bfloat16* __restrict__ oq, __hip_bfloat16* __restrict__ ok,
    __hip_bfloat16* __restrict__ ov, int n8) {
    int idx = blockIdx.x * 256 + threadIdx.x;
    if (idx >= n8) return;
    const float* s = (blockIdx.y == 0) ? q : (blockIdx.y == 1) ? k : v;
    __hip_bfloat16* d = (blockIdx.y == 0) ? oq : (blockIdx.y == 1) ? ok : ov;
    *(short8*)(d + (size_t)idx * 8) = cvt8(s + (size_t)idx * 8);
}

// ---------------- zero the V^T pad columns [S_N, SP_N) once per launch ----------------
__global__ void padv_kernel(__hip_bfloat16* __restrict__ Vt, int total) {
    int idx = blockIdx.x * 256 + threadIdx.x;
    if (idx < total) {
        int p  = idx % (SP_N - S_N);
        int rd = idx / (SP_N - S_N);          // row index over C*NH*HD d-rows
        Vt[(size_t)rd * SP_N + S_N + p] = f2bf(0.f);
    }
}

// ---------------- fused QKV up-projection, 128x128 tile, 2-phase double-buffered -------
// z = 0: Q (oscale=QSCALE, layout 0)  z = 1: K (layout 0)  z = 2: V (layout 1)
// layout 0: out[((bl*NH + h)*S + s)*HD + d]
// layout 1: out[((bl*NH + h)*HD + d)*SP + s]   (V transposed, padded rows)
__global__ __launch_bounds__(256) void qkvproj_kernel(
    const __hip_bfloat16* __restrict__ Xq, const __hip_bfloat16* __restrict__ Xk,
    const __hip_bfloat16* __restrict__ Xv,
    const __hip_bfloat16* __restrict__ WqT, const __hip_bfloat16* __restrict__ WkT,
    const __hip_bfloat16* __restrict__ WvT,
    const float* __restrict__ bq, const float* __restrict__ bk,
    const float* __restrict__ bv,
    __hip_bfloat16* __restrict__ Qc, __hip_bfloat16* __restrict__ Kc,
    __hip_bfloat16* __restrict__ Vc, int Mc, float qscale) {
    __shared__ __hip_bfloat16 As[2][128][32];
    __shared__ __hip_bfloat16 Bs[2][128][32];
    const int z = blockIdx.z;
    const __hip_bfloat16* X  = (z == 0) ? Xq  : (z == 1) ? Xk  : Xv;
    const __hip_bfloat16* WT = (z == 0) ? WqT : (z == 1) ? WkT : WvT;
    const float* bias        = (z == 0) ? bq  : (z == 1) ? bk  : bv;
    __hip_bfloat16* out      = (z == 0) ? Qc  : (z == 1) ? Kc  : Vc;
    const float oscale = (z == 0) ? qscale : 1.0f;
    const int mode = (z == 2);

    const int tid  = threadIdx.x;
    const int wave = tid >> 6, lane = tid & 63;
    const int quad = lane >> 4, l16 = lane & 15;
    const int tm = blockIdx.x * 128, tn = blockIdx.y * 128;
    const int mw = (wave >> 1) * 64, nw = (wave & 1) * 64;
    const int lrow = lane >> 2, lchunk = lane & 3;   // staging: 16 rows x 4 chunks / instr

    floatx4 acc[4][4] = {};

    const int g0 = wave, g1 = wave + 4;
    int ra0 = tm + g0 * 16 + lrow; if (ra0 >= Mc) ra0 = Mc - 1;
    int ra1 = tm + g1 * 16 + lrow; if (ra1 >= Mc) ra1 = Mc - 1;
    const int rb0 = tn + g0 * 16 + lrow, rb1 = tn + g1 * 16 + lrow;

    auto stage = [&](int bb, int kk) {
        gl_lds16(X  + (size_t)ra0 * R_N + kk + lchunk * 8, &As[bb][g0 * 16][0]);
        gl_lds16(X  + (size_t)ra1 * R_N + kk + lchunk * 8, &As[bb][g1 * 16][0]);
        gl_lds16(WT + (size_t)rb0 * R_N + kk + lchunk * 8, &Bs[bb][g0 * 16][0]);
        gl_lds16(WT + (size_t)rb1 * R_N + kk + lchunk * 8, &Bs[bb][g1 * 16][0]);
    };

    stage(0, 0);
    __syncthreads();                                   // drains vmcnt(0)

    for (int t = 0; t < R_N / 32; ++t) {
        const int bb = t & 1;
        if (t + 1 < R_N / 32) stage(bb ^ 1, (t + 1) * 32);   // prefetch next K-tile
        short8 af[4], bfr[4];
#pragma unroll
        for (int mb = 0; mb < 4; ++mb) af[mb]  = *(short8*)&As[bb][mw + mb * 16 + l16][quad * 8];
#pragma unroll
        for (int nb = 0; nb < 4; ++nb) bfr[nb] = *(short8*)&Bs[bb][nw + nb * 16 + l16][quad * 8];
        if (mode == 0) {
#pragma unroll
            for (int mb = 0; mb < 4; ++mb)
#pragma unroll
                for (int nb = 0; nb < 4; ++nb)
                    acc[mb][nb] = __builtin_amdgcn_mfma_f32_16x16x32_bf16(af[mb], bfr[nb], acc[mb][nb], 0, 0, 0);
        } else {   // transposed product: C rows = n, cols = m (coalesced V^T store)
#pragma unroll
            for (int mb = 0; mb < 4; ++mb)
#pragma unroll
                for (int nb = 0; nb < 4; ++nb)
                    acc[mb][nb] = __builtin_amdgcn_mfma_f32_16x16x32_bf16(bfr[nb], af[mb], acc[mb][nb], 0, 0, 0);
        }
        __syncthreads();   // prefetch landed + all waves done with buf bb
    }

#pragma unroll
    for (int mb = 0; mb < 4; ++mb)
#pragma unroll
        for (int nb = 0; nb < 4; ++nb)
#pragma unroll
            for (int r = 0; r < 4; ++r) {
                int m, n;
                if (mode == 0) { m = tm + mw + mb * 16 + quad * 4 + r; n = tn + nw + nb * 16 + l16; }
                else           { n = tn + nw + nb * 16 + quad * 4 + r; m = tm + mw + mb * 16 + l16; }
                if (m >= Mc) continue;
                float v = oscale * (acc[mb][nb][r] + bias[n]);
                int bl = m / S_N, s = m - bl * S_N;
                int h = n >> 6, d = n & 63;
                size_t off = (mode == 0)
                    ? ((size_t)((bl * NH_N + h) * S_N + s)) * HD_N + d
                    : ((size_t)((bl * NH_N + h) * HD_N + d)) * SP_N + s;
                out[off] = f2bf(v);
            }
}

// ---------------- flash attention: swapped QK^T (32x32x16), in-register softmax --------
__global__ __launch_bounds__(256, 3) void attn_kernel(
    const __hip_bfloat16* __restrict__ Qh,  // [C*NH, S, HD]  (pre-scaled by log2e/8)
    const __hip_bfloat16* __restrict__ Kh,  // [C*NH, S, HD]
    const __hip_bfloat16* __restrict__ Vt,  // [C*NH, HD, SP] (pad cols zeroed)
    __hip_bfloat16* __restrict__ ctx) {     // [C, S, NH*HD]
    __shared__ __hip_bfloat16 Kl[2][64][64];   // [buf][key][d], chunk^=(key&7)
    __shared__ __hip_bfloat16 Vl[2][64][64];   // [buf][d][key], chunk^=(d&7)

    const int bh  = blockIdx.x;
    const int q0  = blockIdx.y * 128;
    const int tid = threadIdx.x;
    const int wave = tid >> 6, lane = tid & 63;
    const int c = lane & 31, hi = lane >> 5, c7 = c & 7;
    const size_t base  = (size_t)bh * S_N * HD_N;
    const size_t vbase = (size_t)bh * HD_N * SP_N;

    // staging lane constants: lane covers (row lr, chunk lane&7) of an 8-row slab
    const int lr = lane >> 3;          // 0..7
    const int sc = (lane & 7) ^ lr;    // pre-swizzled source chunk ((row&7)==lr)

    // ---- Q B-frags in registers: lane holds Q[q0+wave*32+c][16*i + 8*hi + j] ----
    short8 qf[4];
    {
        int qrow = q0 + wave * 32 + c;
        if (qrow > S_N - 1) qrow = S_N - 1;            // dup row; outputs guarded
        const __hip_bfloat16* qp = Qh + base + (size_t)qrow * HD_N + hi * 8;
#pragma unroll
        for (int i = 0; i < 4; ++i) qf[i] = *(const short8*)(qp + 16 * i);
    }

    floatx16 oacc[2] = {};   // O[q (regs)][d = 32*db + c]
    float lsum = 0.f;        // partial row-sum for q=c (this hi-half's keys)

    auto stage = [&](int bb, int kt) {
#pragma unroll
        for (int j = 0; j < 2; ++j) {
            int r = 16 * wave + 8 * j + lr;            // tile row 0..63
            int krow = kt + r;
            if (krow > S_N - 1) krow = S_N - 1;        // dup; masked by key index
            gl_lds16(Kh + base + (size_t)krow * HD_N + sc * 8,
                     &Kl[bb][16 * wave + 8 * j][0]);
            gl_lds16(Vt + vbase + (size_t)r * SP_N + kt + sc * 8,
                     &Vl[bb][16 * wave + 8 * j][0]);
        }
    };

    stage(0, 0);
    __syncthreads();                                    // implies vmcnt(0) drain

    int bb = 0;
    for (int t = 0; t < KTILES; ++t) {
        const int kt = t * 64;
        if (t + 1 < KTILES) stage(bb ^ 1, kt + 64);     // prefetch next tile
        const bool last = (kt + 64 > S_N);

        short8 pa[2][2];                                // P A-frags [sub][16-key step]
#pragma unroll
        for (int sub = 0; sub < 2; ++sub) {
            // S^T = K_tile(32) x Q^T: lane col = q (=c), regs = key rows
            floatx16 sacc = {};
            __builtin_amdgcn_s_setprio(1);
#pragma unroll
            for (int i = 0; i < 4; ++i) {
                short8 kf = *(const short8*)&Kl[bb][32 * sub + c][(((2 * i + hi) ^ c7) << 3)];
                sacc = __builtin_amdgcn_mfma_f32_32x32x16_bf16(kf, qf[i], sacc, 0, 0, 0);
            }
            __builtin_amdgcn_s_setprio(0);
            float ps[16];
            if (!last) {
#pragma unroll
                for (int r = 0; r < 16; ++r) ps[r] = fast_exp2(sacc[r]);
            } else {
#pragma unroll
                for (int r = 0; r < 16; ++r) {
                    int key = kt + 32 * sub + (r & 3) + 8 * (r >> 2) + 4 * hi;
                    ps[r] = (key < S_N) ? fast_exp2(sacc[r]) : 0.f;
                }
            }
#pragma unroll
            for (int r = 0; r < 16; ++r) lsum += ps[r];
            // in-register repack: reg r holds key (r&3)+8*(r>>2)+4*hi; PV A-frag
            // needs keys 8*hi+j per 16-key step -> pair-pack + lane<->lane+32 swap
#pragma unroll
            for (int step = 0; step < 2; ++step) {
                unsigned w0 = cvtpk(ps[8 * step + 0], ps[8 * step + 1]);
                unsigned w1 = cvtpk(ps[8 * step + 2], ps[8 * step + 3]);
                unsigned w2 = cvtpk(ps[8 * step + 4], ps[8 * step + 5]);
                unsigned w3 = cvtpk(ps[8 * step + 6], ps[8 * step + 7]);
                asm("v_permlane32_swap_b32 %0, %1" : "+v"(w0), "+v"(w2));
                asm("v_permlane32_swap_b32 %0, %1" : "+v"(w1), "+v"(w3));
                union { unsigned u[4]; short8 s; } fu;
                fu.u[0] = w0; fu.u[1] = w1; fu.u[2] = w2; fu.u[3] = w3;
                pa[sub][step] = fu.s;
            }
        }

        // O += P @ V  (B-frag: V[key][d], col = d = 32*db + c)
        __builtin_amdgcn_s_setprio(1);
#pragma unroll
        for (int db = 0; db < 2; ++db)
#pragma unroll
            for (int sub = 0; sub < 2; ++sub)
#pragma unroll
                for (int step = 0; step < 2; ++step) {
                    short8 vf = *(const short8*)
                        &Vl[bb][32 * db + c][((((sub * 2 + step) * 2 + hi) ^ c7) << 3)];
                    oacc[db] = __builtin_amdgcn_mfma_f32_32x32x16_bf16(pa[sub][step], vf, oacc[db], 0, 0, 0);
                }
        __builtin_amdgcn_s_setprio(0);

        __syncthreads();    // prefetch landed (vmcnt0) + all waves done with buf bb
        bb ^= 1;
    }

    // combine the two hi-halves' partial sums; reciprocal once per q-row
    lsum += __shfl_xor(lsum, 32);
    float rs = 1.0f / lsum;

    const int bl = bh / NH_N, h = bh - bl * NH_N;
    const int srow0 = q0 + wave * 32;
#pragma unroll
    for (int r = 0; r < 16; ++r) {
        int q = (r & 3) + 8 * (r >> 2) + 4 * hi;       // O row of reg r
        float rr = __shfl(rs, q, 32);                  // rs lives at lane c==q (both halves)
        int s = srow0 + q;
        if (s < S_N) {
            size_t o = ((size_t)(bl * S_N + s)) * H_N + h * HD_N + c;
            ctx[o]      = f2bf(oacc[0][r] * rr);
            ctx[o + 32] = f2bf(oacc[1][r] * rr);
        }
    }
}

// ---------------- down-projection, 128x128 tile, 2-phase double-buffered + gelu --------
__global__ __launch_bounds__(256) void dproj_kernel(
    const __hip_bfloat16* __restrict__ X,    // ctx [Mc, H_N] bf16
    const __hip_bfloat16* __restrict__ WT,   // WoT [R_N, H_N] bf16
    float* __restrict__ out,                 // [Mc, R_N] fp32
    int Mc) {
    __shared__ __hip_bfloat16 As[2][128][32];
    __shared__ __hip_bfloat16 Bs[2][128][32];
    const int tid  = threadIdx.x;
    const int wave = tid >> 6, lane = tid & 63;
    const int quad = lane >> 4, l16 = lane & 15;
    const int tm = blockIdx.x * 128, tn = blockIdx.y * 128;
    const int mw = (wave >> 1) * 64, nw = (wave & 1) * 64;
    const int lrow = lane >> 2, lchunk = lane & 3;

    floatx4 acc[4][4] = {};

    const int g0 = wave, g1 = wave + 4;
    int ra0 = tm + g0 * 16 + lrow; if (ra0 >= Mc) ra0 = Mc - 1;
    int ra1 = tm + g1 * 16 + lrow; if (ra1 >= Mc) ra1 = Mc - 1;
    const int rb0 = tn + g0 * 16 + lrow, rb1 = tn + g1 * 16 + lrow;

    auto stage = [&](int bb, int kk) {
        gl_lds16(X  + (size_t)ra0 * H_N + kk + lchunk * 8, &As[bb][g0 * 16][0]);
        gl_lds16(X  + (size_t)ra1 * H_N + kk + lchunk * 8, &As[bb][g1 * 16][0]);
        gl_lds16(WT + (size_t)rb0 * H_N + kk + lchunk * 8, &Bs[bb][g0 * 16][0]);
        gl_lds16(WT + (size_t)rb1 * H_N + kk + lchunk * 8, &Bs[bb][g1 * 16][0]);
    };

    stage(0, 0);
    __syncthreads();

    for (int t = 0; t < H_N / 32; ++t) {
        const int bb = t & 1;
        if (t + 1 < H_N / 32) stage(bb ^ 1, (t + 1) * 32);
        short8 af[4], bfr[4];
#pragma unroll
        for (int mb = 0; mb < 4; ++mb) af[mb]  = *(short8*)&As[bb][mw + mb * 16 + l16][quad * 8];
#pragma unroll
        for (int nb = 0; nb < 4; ++nb) bfr[nb] = *(short8*)&Bs[bb][nw + nb * 16 + l16][quad * 8];
#pragma unroll
        for (int mb = 0; mb < 4; ++mb)
#pragma unroll
            for (int nb = 0; nb < 4; ++nb)
                acc[mb][nb] = __builtin_amdgcn_mfma_f32_16x16x32_bf16(af[mb], bfr[nb], acc[mb][nb], 0, 0, 0);
        __syncthreads();
    }

#pragma unroll
    for (int mb = 0; mb < 4; ++mb)
#pragma unroll
        for (int nb = 0; nb < 4; ++nb)
#pragma unroll
            for (int r = 0; r < 4; ++r) {
                int m = tm + mw + mb * 16 + quad * 4 + r;
                int n = tn + nw + nb * 16 + l16;
                if (m >= Mc) continue;
                float x = acc[mb][nb][r];
                float g = 0.5f * x * (1.0f + erff(x * 0.70710678118654752f));
                out[(size_t)m * R_N + n] = g;
            }
}

extern "C" void kernel_launch(void* const* d_in, const int* in_sizes, int n_in,
                              void* d_out, int out_size, void* d_ws, size_t ws_size,
                              hipStream_t stream) {
    const float* q_low = (const float*)d_in[0];
    const float* k_low = (const float*)d_in[1];
    const float* v_low = (const float*)d_in[2];
    const float* Wq    = (const float*)d_in[3];
    const float* bq    = (const float*)d_in[4];
    const float* Wk    = (const float*)d_in[5];
    const float* bk    = (const float*)d_in[6];
    const float* Wv    = (const float*)d_in[7];
    const float* bv    = (const float*)d_in[8];
    const float* Wo    = (const float*)d_in[9];
    float* out = (float*)d_out;
    (void)in_sizes; (void)n_in; (void)out_size;

    const float QSCALE = 0.125f * 1.44269504088896f;   // log2(e)/sqrt(HD)
    const size_t SZ_W = (size_t)H_N * R_N * 2;

    int C = 32;
    while (C > 1) {
        size_t qk = (size_t)C * NH_N * S_N * HD_N * 2;
        size_t vv = (size_t)C * NH_N * HD_N * SP_N * 2;
        size_t cx = (size_t)C * S_N * H_N * 2;
        if (4 * SZ_W + 2 * qk + vv + cx <= ws_size) break;
        C >>= 1;
    }

    char* ws = (char*)d_ws;
    const size_t SZ_QK = (size_t)C * NH_N * S_N * HD_N * 2;
    const size_t SZ_V  = (size_t)C * NH_N * HD_N * SP_N * 2;
    __hip_bfloat16* WqT = (__hip_bfloat16*)(ws);
    __hip_bfloat16* WkT = (__hip_bfloat16*)(ws + SZ_W);
    __hip_bfloat16* WvT = (__hip_bfloat16*)(ws + 2 * SZ_W);
    __hip_bfloat16* WoT = (__hip_bfloat16*)(ws + 3 * SZ_W);
    __hip_bfloat16* Qc  = (__hip_bfloat16*)(ws + 4 * SZ_W);
    __hip_bfloat16* Kc  = (__hip_bfloat16*)(ws + 4 * SZ_W + SZ_QK);
    __hip_bfloat16* Vc  = (__hip_bfloat16*)(ws + 4 * SZ_W + 2 * SZ_QK);
    __hip_bfloat16* ctc = (__hip_bfloat16*)(ws + 4 * SZ_W + 2 * SZ_QK + SZ_V);

    // Weight transposes
    {
        dim3 tg(R_N / 32, H_N / 32, 3);
        transpose3_kernel<<<tg, 256, 0, stream>>>(Wq, Wk, Wv, WqT, WkT, WvT, R_N, H_N);
        dim3 to(H_N / 32, R_N / 32);
        transpose_kernel<<<to, 256, 0, stream>>>(Wo, WoT, H_N, R_N);
    }

    // zero V^T pad columns once (Vc reused across chunks; proj never touches them)
    {
        int total = C * NH_N * HD_N * (SP_N - S_N);
        padv_kernel<<<(total + 255) / 256, 256, 0, stream>>>(Vc, total);
    }

    for (int c0 = 0; c0 < B_N; c0 += C) {
        const int Mc = C * S_N;
        const size_t xoff = (size_t)c0 * S_N * R_N;

        // bf16 copies of the low-rank activations, aliased onto ctc (live only
        // until attn overwrites ctc -- proj finishes reading them before that).
        __hip_bfloat16* Xq = ctc;
        __hip_bfloat16* Xk = ctc + (size_t)Mc * R_N;
        __hip_bfloat16* Xv = ctc + 2 * (size_t)Mc * R_N;
        {
            int n8 = Mc * R_N / 8;
            dim3 cg((n8 + 255) / 256, 3);
            cvtx_kernel<<<cg, 256, 0, stream>>>(q_low + xoff, k_low + xoff, v_low + xoff,
                                                Xq, Xk, Xv, n8);
        }

        dim3 pg((Mc + 127) / 128, H_N / 128, 3);
        qkvproj_kernel<<<pg, 256, 0, stream>>>(Xq, Xk, Xv, WqT, WkT, WvT,
                                               bq, bk, bv, Qc, Kc, Vc, Mc, QSCALE);

        dim3 ag(C * NH_N, (S_N + 127) / 128);
        attn_kernel<<<ag, 256, 0, stream>>>(Qc, Kc, Vc, ctc);

        dim3 dg((Mc + 127) / 128, R_N / 128);
        dproj_kernel<<<dg, 256, 0, stream>>>(ctc, WoT, out + xoff, Mc);
    }
}

// Round 6
// 559.670 us; speedup vs baseline: 1.1495x; 1.1495x over previous
//
#include <hip/hip_runtime.h>
#include <hip/hip_bf16.h>
#include <math.h>

using short8   = __attribute__((ext_vector_type(8))) short;
using floatx4  = __attribute__((ext_vector_type(4))) float;
using floatx16 = __attribute__((ext_vector_type(16))) float;

#define B_N  32
#define S_N  1026
#define R_N  256
#define H_N  1024
#define NH_N 16
#define HD_N 64
#define SP_N 1088          // padded S for V^T rows: 17 * 64, pad cols zeroed once
#define KTILES 17          // SP_N / 64

__device__ __forceinline__ float bf2f(__hip_bfloat16 x) { return __bfloat162float(x); }
__device__ __forceinline__ __hip_bfloat16 f2bf(float x) { return __float2bfloat16(x); }

__device__ __forceinline__ float fast_exp2(float x) {
#if __has_builtin(__builtin_amdgcn_exp2f)
    return __builtin_amdgcn_exp2f(x);
#else
    return exp2f(x);
#endif
}

// pack two f32 -> one u32 of two bf16 (RNE), single instruction
__device__ __forceinline__ unsigned cvtpk(float lo, float hi_) {
    unsigned r;
    asm("v_cvt_pk_bf16_f32 %0, %1, %2" : "=v"(r) : "v"(lo), "v"(hi_));
    return r;
}

// async global->LDS, 16B per lane; LDS dest = uniform base + lane*16
__device__ __forceinline__ void gl_lds16(const void* g, void* l) {
    __builtin_amdgcn_global_load_lds(
        (const __attribute__((address_space(1))) unsigned int*)g,
        (__attribute__((address_space(3))) unsigned int*)l, 16, 0, 0);
}

// m157 XCD swizzle (bijective iff nwg % 8 == 0, else identity): contiguous
// chunk of tile space per XCD.
__device__ __forceinline__ int xcd_swz(int o, int nwg) {
    return ((nwg & 7) == 0) ? ((o & 7) * (nwg >> 3) + (o >> 3)) : o;
}

// convert 8 fp32 (two float4) -> short8 of bf16
__device__ __forceinline__ short8 cvt8(const float* __restrict__ p) {
    floatx4 a = *(const floatx4*)p;
    floatx4 b = *(const floatx4*)(p + 4);
    short8 o;
    __hip_bfloat16* op = (__hip_bfloat16*)&o;
    op[0] = f2bf(a[0]); op[1] = f2bf(a[1]); op[2] = f2bf(a[2]); op[3] = f2bf(a[3]);
    op[4] = f2bf(b[0]); op[5] = f2bf(b[1]); op[6] = f2bf(b[2]); op[7] = f2bf(b[3]);
    return o;
}

// ---------------- LDS-tiled transpose + downcast for Wq/Wk/Wv (one launch, z-select) ---
__global__ __launch_bounds__(256) void transpose3_kernel(
    const float* __restrict__ a, const float* __restrict__ b, const float* __restrict__ c,
    __hip_bfloat16* __restrict__ oa, __hip_bfloat16* __restrict__ ob,
    __hip_bfloat16* __restrict__ oc, int K, int N) {
    __shared__ __hip_bfloat16 t[32][33];
    const float* in = (blockIdx.z == 0) ? a : (blockIdx.z == 1) ? b : c;
    __hip_bfloat16* out = (blockIdx.z == 0) ? oa : (blockIdx.z == 1) ? ob : oc;
    const int k0 = blockIdx.x * 32, n0 = blockIdx.y * 32;
    const int tx = threadIdx.x & 31, ty = threadIdx.x >> 5;   // 32 x 8
#pragma unroll
    for (int j = 0; j < 32; j += 8)
        t[ty + j][tx] = f2bf(in[(size_t)(k0 + ty + j) * N + n0 + tx]);
    __syncthreads();
#pragma unroll
    for (int j = 0; j < 32; j += 8)
        out[(size_t)(n0 + ty + j) * K + k0 + tx] = t[tx][ty + j];
}

__global__ __launch_bounds__(256) void transpose_kernel(const float* __restrict__ in,
                                                        __hip_bfloat16* __restrict__ out,
                                                        int K, int N) {
    __shared__ __hip_bfloat16 t[32][33];
    const int k0 = blockIdx.x * 32, n0 = blockIdx.y * 32;
    const int tx = threadIdx.x & 31, ty = threadIdx.x >> 5;
#pragma unroll
    for (int j = 0; j < 32; j += 8)
        t[ty + j][tx] = f2bf(in[(size_t)(k0 + ty + j) * N + n0 + tx]);
    __syncthreads();
#pragma unroll
    for (int j = 0; j < 32; j += 8)
        out[(size_t)(n0 + ty + j) * K + k0 + tx] = t[tx][ty + j];
}

// ---------------- fused fp32 -> bf16 convert for q/k/v_low (one launch) ----------------
__global__ __launch_bounds__(256) void cvtx_kernel(
    const float* __restrict__ q, const float* __restrict__ k, const float* __restrict__ v,
    __hip_bfloat16* __restrict__ oq, __hip_bfloat16* __restrict__ ok,
    __hip_bfloat16* __restrict__ ov, int n8) {
    int idx = blockIdx.x * 256 + threadIdx.x;
    if (idx >= n8) return;
    const float* s = (blockIdx.y == 0) ? q : (blockIdx.y == 1) ? k : v;
    __hip_bfloat16* d = (blockIdx.y == 0) ? oq : (blockIdx.y == 1) ? ok : ov;
    *(short8*)(d + (size_t)idx * 8) = cvt8(s + (size_t)idx * 8);
}

// ---------------- zero the V^T pad columns [S_N, SP_N) once per launch ----------------
__global__ void padv_kernel(__hip_bfloat16* __restrict__ Vt, int total) {
    int idx = blockIdx.x * 256 + threadIdx.x;
    if (idx < total) {
        int p  = idx % (SP_N - S_N);
        int rd = idx / (SP_N - S_N);          // row index over C*NH*HD d-rows
        Vt[(size_t)rd * SP_N + S_N + p] = f2bf(0.f);
    }
}

// ---------------- fused QKV up-projection, 128x128 tile, BK=64, XOR-swizzled LDS -------
// Tile decode (n-tile fastest after XCD swizzle): tz selects Q/K/V.
// layout 0: out[((bl*NH + h)*S + s)*HD + d]
// layout 1: out[((bl*NH + h)*HD + d)*SP + s]   (V transposed, padded rows)
__global__ __launch_bounds__(256) void qkvproj_kernel(
    const __hip_bfloat16* __restrict__ Xq, const __hip_bfloat16* __restrict__ Xk,
    const __hip_bfloat16* __restrict__ Xv,
    const __hip_bfloat16* __restrict__ WqT, const __hip_bfloat16* __restrict__ WkT,
    const __hip_bfloat16* __restrict__ WvT,
    const float* __restrict__ bq, const float* __restrict__ bk,
    const float* __restrict__ bv,
    __hip_bfloat16* __restrict__ Qc, __hip_bfloat16* __restrict__ Kc,
    __hip_bfloat16* __restrict__ Vc, int Mc, float qscale) {
    __shared__ __hip_bfloat16 As[2][128][64];   // [buf][row][k], chunk^=(row&7)
    __shared__ __hip_bfloat16 Bs[2][128][64];

    // ---- XCD-swizzled tile decode: y (n-tile, 8) fastest, then x (m-tile), then z ----
    const int nx = gridDim.x;                  // m-tiles
    const int nwg = nx * 8 * 3;
    const int o = blockIdx.x + nx * (blockIdx.y + 8 * blockIdx.z);
    const int tlin = xcd_swz(o, nwg);
    const int ty = tlin & 7;
    const int rest = tlin >> 3;
    const int tx = rest % nx, tz = rest / nx;

    const __hip_bfloat16* X  = (tz == 0) ? Xq  : (tz == 1) ? Xk  : Xv;
    const __hip_bfloat16* WT = (tz == 0) ? WqT : (tz == 1) ? WkT : WvT;
    const float* bias        = (tz == 0) ? bq  : (tz == 1) ? bk  : bv;
    __hip_bfloat16* out      = (tz == 0) ? Qc  : (tz == 1) ? Kc  : Vc;
    const float oscale = (tz == 0) ? qscale : 1.0f;
    const int mode = (tz == 2);

    const int tid  = threadIdx.x;
    const int wave = tid >> 6, lane = tid & 63;
    const int quad = lane >> 4, l16 = lane & 15;
    const int tm = tx * 128, tn = ty * 128;
    const int mw = (wave >> 1) * 64, nw = (wave & 1) * 64;
    const int lr = lane >> 3;                  // row within 8-row slab
    const int sc = (lane & 7) ^ lr;            // pre-swizzled source chunk

    floatx4 acc[4][4] = {};

    auto stage = [&](int bb, int kk) {
#pragma unroll
        for (int s8 = 0; s8 < 4; ++s8) {
            int row = wave * 32 + s8 * 8;      // slab base (wave-uniform)
            int gm = tm + row + lr; if (gm >= Mc) gm = Mc - 1;
            gl_lds16(X + (size_t)gm * R_N + kk + sc * 8, &As[bb][row][0]);
            gl_lds16(WT + (size_t)(tn + row + lr) * R_N + kk + sc * 8, &Bs[bb][row][0]);
        }
    };

    stage(0, 0);
    __syncthreads();                           // drains vmcnt(0)

    for (int t = 0; t < R_N / 64; ++t) {
        const int bb = t & 1;
        if (t + 1 < R_N / 64) stage(bb ^ 1, (t + 1) * 64);   // prefetch next K-tile
        short8 af[4][2], bfr[4][2];
#pragma unroll
        for (int mb = 0; mb < 4; ++mb) {
            int row = mw + mb * 16 + l16;
            const char* rp = (const char*)&As[bb][row][0];
#pragma unroll
            for (int k2 = 0; k2 < 2; ++k2)
                af[mb][k2] = *(const short8*)(rp + ((((k2 * 4 + quad)) ^ (row & 7)) << 4));
        }
#pragma unroll
        for (int nb = 0; nb < 4; ++nb) {
            int row = nw + nb * 16 + l16;
            const char* rp = (const char*)&Bs[bb][row][0];
#pragma unroll
            for (int k2 = 0; k2 < 2; ++k2)
                bfr[nb][k2] = *(const short8*)(rp + ((((k2 * 4 + quad)) ^ (row & 7)) << 4));
        }
        if (mode == 0) {
#pragma unroll
            for (int mb = 0; mb < 4; ++mb)
#pragma unroll
                for (int nb = 0; nb < 4; ++nb) {
                    acc[mb][nb] = __builtin_amdgcn_mfma_f32_16x16x32_bf16(af[mb][0], bfr[nb][0], acc[mb][nb], 0, 0, 0);
                    acc[mb][nb] = __builtin_amdgcn_mfma_f32_16x16x32_bf16(af[mb][1], bfr[nb][1], acc[mb][nb], 0, 0, 0);
                }
        } else {   // transposed product: C rows = n, cols = m (coalesced V^T store)
#pragma unroll
            for (int mb = 0; mb < 4; ++mb)
#pragma unroll
                for (int nb = 0; nb < 4; ++nb) {
                    acc[mb][nb] = __builtin_amdgcn_mfma_f32_16x16x32_bf16(bfr[nb][0], af[mb][0], acc[mb][nb], 0, 0, 0);
                    acc[mb][nb] = __builtin_amdgcn_mfma_f32_16x16x32_bf16(bfr[nb][1], af[mb][1], acc[mb][nb], 0, 0, 0);
                }
        }
        __syncthreads();   // prefetch landed + all waves done with buf bb
    }

#pragma unroll
    for (int mb = 0; mb < 4; ++mb)
#pragma unroll
        for (int nb = 0; nb < 4; ++nb)
#pragma unroll
            for (int r = 0; r < 4; ++r) {
                int m, n;
                if (mode == 0) { m = tm + mw + mb * 16 + quad * 4 + r; n = tn + nw + nb * 16 + l16; }
                else           { n = tn + nw + nb * 16 + quad * 4 + r; m = tm + mw + mb * 16 + l16; }
                if (m >= Mc) continue;
                float v = oscale * (acc[mb][nb][r] + bias[n]);
                int bl = m / S_N, s = m - bl * S_N;
                int h = n >> 6, d = n & 63;
                size_t off = (mode == 0)
                    ? ((size_t)((bl * NH_N + h) * S_N + s)) * HD_N + d
                    : ((size_t)((bl * NH_N + h) * HD_N + d)) * SP_N + s;
                out[off] = f2bf(v);
            }
}

// ---------------- flash attention: swapped QK^T (32x32x16), in-register softmax --------
__global__ __launch_bounds__(256, 3) void attn_kernel(
    const __hip_bfloat16* __restrict__ Qh,  // [C*NH, S, HD]  (pre-scaled by log2e/8)
    const __hip_bfloat16* __restrict__ Kh,  // [C*NH, S, HD]
    const __hip_bfloat16* __restrict__ Vt,  // [C*NH, HD, SP] (pad cols zeroed)
    __hip_bfloat16* __restrict__ ctx) {     // [C, S, NH*HD]
    __shared__ __hip_bfloat16 Kl[2][64][64];   // [buf][key][d], chunk^=(key&7)
    __shared__ __hip_bfloat16 Vl[2][64][64];   // [buf][d][key], chunk^=(d&7)

    // XCD-swizzled decode: q-tile (gridDim.y) fastest so a head's q-tiles share L2
    const int ny = gridDim.y;
    const int nwg = gridDim.x * ny;
    const int o = blockIdx.x + gridDim.x * blockIdx.y;
    const int tlin = xcd_swz(o, nwg);
    const int bh = tlin / ny;
    const int q0 = (tlin % ny) * 128;

    const int tid = threadIdx.x;
    const int wave = tid >> 6, lane = tid & 63;
    const int c = lane & 31, hi = lane >> 5, c7 = c & 7;
    const size_t base  = (size_t)bh * S_N * HD_N;
    const size_t vbase = (size_t)bh * HD_N * SP_N;

    // staging lane constants: lane covers (row lr, chunk lane&7) of an 8-row slab
    const int lr = lane >> 3;          // 0..7
    const int sc = (lane & 7) ^ lr;    // pre-swizzled source chunk ((row&7)==lr)

    // ---- Q B-frags in registers: lane holds Q[q0+wave*32+c][16*i + 8*hi + j] ----
    short8 qf[4];
    {
        int qrow = q0 + wave * 32 + c;
        if (qrow > S_N - 1) qrow = S_N - 1;            // dup row; outputs guarded
        const __hip_bfloat16* qp = Qh + base + (size_t)qrow * HD_N + hi * 8;
#pragma unroll
        for (int i = 0; i < 4; ++i) qf[i] = *(const short8*)(qp + 16 * i);
    }

    floatx16 oacc[2] = {};   // O[q (regs)][d = 32*db + c]
    float lsum = 0.f;        // partial row-sum for q=c (this hi-half's keys)

    auto stage = [&](int bb, int kt) {
#pragma unroll
        for (int j = 0; j < 2; ++j) {
            int r = 16 * wave + 8 * j + lr;            // tile row 0..63
            int krow = kt + r;
            if (krow > S_N - 1) krow = S_N - 1;        // dup; masked by key index
            gl_lds16(Kh + base + (size_t)krow * HD_N + sc * 8,
                     &Kl[bb][16 * wave + 8 * j][0]);
            gl_lds16(Vt + vbase + (size_t)r * SP_N + kt + sc * 8,
                     &Vl[bb][16 * wave + 8 * j][0]);
        }
    };

    stage(0, 0);
    __syncthreads();                                    // implies vmcnt(0) drain

    int bb = 0;
    for (int t = 0; t < KTILES; ++t) {
        const int kt = t * 64;
        if (t + 1 < KTILES) stage(bb ^ 1, kt + 64);     // prefetch next tile
        const bool last = (kt + 64 > S_N);

        short8 pa[2][2];                                // P A-frags [sub][16-key step]
#pragma unroll
        for (int sub = 0; sub < 2; ++sub) {
            // S^T = K_tile(32) x Q^T: lane col = q (=c), regs = key rows
            floatx16 sacc = {};
            __builtin_amdgcn_s_setprio(1);
#pragma unroll
            for (int i = 0; i < 4; ++i) {
                short8 kf = *(const short8*)&Kl[bb][32 * sub + c][(((2 * i + hi) ^ c7) << 3)];
                sacc = __builtin_amdgcn_mfma_f32_32x32x16_bf16(kf, qf[i], sacc, 0, 0, 0);
            }
            __builtin_amdgcn_s_setprio(0);
            float ps[16];
            if (!last) {
#pragma unroll
                for (int r = 0; r < 16; ++r) ps[r] = fast_exp2(sacc[r]);
            } else {
#pragma unroll
                for (int r = 0; r < 16; ++r) {
                    int key = kt + 32 * sub + (r & 3) + 8 * (r >> 2) + 4 * hi;
                    ps[r] = (key < S_N) ? fast_exp2(sacc[r]) : 0.f;
                }
            }
#pragma unroll
            for (int r = 0; r < 16; ++r) lsum += ps[r];
            // in-register repack: reg r holds key (r&3)+8*(r>>2)+4*hi; PV A-frag
            // needs keys 8*hi+j per 16-key step -> pair-pack + lane<->lane+32 swap
#pragma unroll
            for (int step = 0; step < 2; ++step) {
                unsigned w0 = cvtpk(ps[8 * step + 0], ps[8 * step + 1]);
                unsigned w1 = cvtpk(ps[8 * step + 2], ps[8 * step + 3]);
                unsigned w2 = cvtpk(ps[8 * step + 4], ps[8 * step + 5]);
                unsigned w3 = cvtpk(ps[8 * step + 6], ps[8 * step + 7]);
                asm("v_permlane32_swap_b32 %0, %1" : "+v"(w0), "+v"(w2));
                asm("v_permlane32_swap_b32 %0, %1" : "+v"(w1), "+v"(w3));
                union { unsigned u[4]; short8 s; } fu;
                fu.u[0] = w0; fu.u[1] = w1; fu.u[2] = w2; fu.u[3] = w3;
                pa[sub][step] = fu.s;
            }
        }

        // O += P @ V  (B-frag: V[key][d], col = d = 32*db + c)
        __builtin_amdgcn_s_setprio(1);
#pragma unroll
        for (int db = 0; db < 2; ++db)
#pragma unroll
            for (int sub = 0; sub < 2; ++sub)
#pragma unroll
                for (int step = 0; step < 2; ++step) {
                    short8 vf = *(const short8*)
                        &Vl[bb][32 * db + c][((((sub * 2 + step) * 2 + hi) ^ c7) << 3)];
                    oacc[db] = __builtin_amdgcn_mfma_f32_32x32x16_bf16(pa[sub][step], vf, oacc[db], 0, 0, 0);
                }
        __builtin_amdgcn_s_setprio(0);

        __syncthreads();    // prefetch landed (vmcnt0) + all waves done with buf bb
        bb ^= 1;
    }

    // combine the two hi-halves' partial sums; reciprocal once per q-row
    lsum += __shfl_xor(lsum, 32);
    float rs = 1.0f / lsum;

    const int bl = bh / NH_N, h = bh - bl * NH_N;
    const int srow0 = q0 + wave * 32;
#pragma unroll
    for (int r = 0; r < 16; ++r) {
        int q = (r & 3) + 8 * (r >> 2) + 4 * hi;       // O row of reg r
        float rr = __shfl(rs, q, 32);                  // rs lives at lane c==q (both halves)
        int s = srow0 + q;
        if (s < S_N) {
            size_t o2 = ((size_t)(bl * S_N + s)) * H_N + h * HD_N + c;
            ctx[o2]      = f2bf(oacc[0][r] * rr);
            ctx[o2 + 32] = f2bf(oacc[1][r] * rr);
        }
    }
}

// ---------------- down-projection, 64x128 tile, BK=64, XOR-swizzled LDS + gelu ---------
__global__ __launch_bounds__(256) void dproj_kernel(
    const __hip_bfloat16* __restrict__ X,    // ctx [Mc, H_N] bf16
    const __hip_bfloat16* __restrict__ WT,   // WoT [R_N, H_N] bf16
    float* __restrict__ out,                 // [Mc, R_N] fp32
    int Mc) {
    __shared__ __hip_bfloat16 As[2][64][64];    // 16 KB
    __shared__ __hip_bfloat16 Bs[2][128][64];   // 32 KB

    // plain decode (grid 514 blocks, not XCD-divisible -- skip swizzle)
    const int tx = blockIdx.x, ty = blockIdx.y;

    const int tid  = threadIdx.x;
    const int wave = tid >> 6, lane = tid & 63;
    const int quad = lane >> 4, l16 = lane & 15;
    const int tm = tx * 64, tn = ty * 128;
    const int mw = (wave >> 1) * 32, nw = (wave & 1) * 64;
    const int lr = lane >> 3;
    const int sc = (lane & 7) ^ lr;

    floatx4 acc[2][4] = {};

    auto stage = [&](int bb, int kk) {
#pragma unroll
        for (int s8 = 0; s8 < 2; ++s8) {
            int row = wave * 16 + s8 * 8;
            int gm = tm + row + lr; if (gm >= Mc) gm = Mc - 1;
            gl_lds16(X + (size_t)gm * H_N + kk + sc * 8, &As[bb][row][0]);
        }
#pragma unroll
        for (int s8 = 0; s8 < 4; ++s8) {
            int row = wave * 32 + s8 * 8;
            gl_lds16(WT + (size_t)(tn + row + lr) * H_N + kk + sc * 8, &Bs[bb][row][0]);
        }
    };

    stage(0, 0);
    __syncthreads();

    for (int t = 0; t < H_N / 64; ++t) {
        const int bb = t & 1;
        if (t + 1 < H_N / 64) stage(bb ^ 1, (t + 1) * 64);
        short8 af[2][2], bfr[4][2];
#pragma unroll
        for (int mb = 0; mb < 2; ++mb) {
            int row = mw + mb * 16 + l16;
            const char* rp = (const char*)&As[bb][row][0];
#pragma unroll
            for (int k2 = 0; k2 < 2; ++k2)
                af[mb][k2] = *(const short8*)(rp + ((((k2 * 4 + quad)) ^ (row & 7)) << 4));
        }
#pragma unroll
        for (int nb = 0; nb < 4; ++nb) {
            int row = nw + nb * 16 + l16;
            const char* rp = (const char*)&Bs[bb][row][0];
#pragma unroll
            for (int k2 = 0; k2 < 2; ++k2)
                bfr[nb][k2] = *(const short8*)(rp + ((((k2 * 4 + quad)) ^ (row & 7)) << 4));
        }
#pragma unroll
        for (int mb = 0; mb < 2; ++mb)
#pragma unroll
            for (int nb = 0; nb < 4; ++nb) {
                acc[mb][nb] = __builtin_amdgcn_mfma_f32_16x16x32_bf16(af[mb][0], bfr[nb][0], acc[mb][nb], 0, 0, 0);
                acc[mb][nb] = __builtin_amdgcn_mfma_f32_16x16x32_bf16(af[mb][1], bfr[nb][1], acc[mb][nb], 0, 0, 0);
            }
        __syncthreads();
    }

#pragma unroll
    for (int mb = 0; mb < 2; ++mb)
#pragma unroll
        for (int nb = 0; nb < 4; ++nb)
#pragma unroll
            for (int r = 0; r < 4; ++r) {
                int m = tm + mw + mb * 16 + quad * 4 + r;
                int n = tn + nw + nb * 16 + l16;
                if (m >= Mc) continue;
                float x = acc[mb][nb][r];
                float g = 0.5f * x * (1.0f + erff(x * 0.70710678118654752f));
                out[(size_t)m * R_N + n] = g;
            }
}

extern "C" void kernel_launch(void* const* d_in, const int* in_sizes, int n_in,
                              void* d_out, int out_size, void* d_ws, size_t ws_size,
                              hipStream_t stream) {
    const float* q_low = (const float*)d_in[0];
    const float* k_low = (const float*)d_in[1];
    const float* v_low = (const float*)d_in[2];
    const float* Wq    = (const float*)d_in[3];
    const float* bq    = (const float*)d_in[4];
    const float* Wk    = (const float*)d_in[5];
    const float* bk    = (const float*)d_in[6];
    const float* Wv    = (const float*)d_in[7];
    const float* bv    = (const float*)d_in[8];
    const float* Wo    = (const float*)d_in[9];
    float* out = (float*)d_out;
    (void)in_sizes; (void)n_in; (void)out_size;

    const float QSCALE = 0.125f * 1.44269504088896f;   // log2(e)/sqrt(HD)
    const size_t SZ_W = (size_t)H_N * R_N * 2;

    int C = 32;
    while (C > 1) {
        size_t qk = (size_t)C * NH_N * S_N * HD_N * 2;
        size_t vv = (size_t)C * NH_N * HD_N * SP_N * 2;
        size_t cx = (size_t)C * S_N * H_N * 2;
        if (4 * SZ_W + 2 * qk + vv + cx <= ws_size) break;
        C >>= 1;
    }

    char* ws = (char*)d_ws;
    const size_t SZ_QK = (size_t)C * NH_N * S_N * HD_N * 2;
    const size_t SZ_V  = (size_t)C * NH_N * HD_N * SP_N * 2;
    __hip_bfloat16* WqT = (__hip_bfloat16*)(ws);
    __hip_bfloat16* WkT = (__hip_bfloat16*)(ws + SZ_W);
    __hip_bfloat16* WvT = (__hip_bfloat16*)(ws + 2 * SZ_W);
    __hip_bfloat16* WoT = (__hip_bfloat16*)(ws + 3 * SZ_W);
    __hip_bfloat16* Qc  = (__hip_bfloat16*)(ws + 4 * SZ_W);
    __hip_bfloat16* Kc  = (__hip_bfloat16*)(ws + 4 * SZ_W + SZ_QK);
    __hip_bfloat16* Vc  = (__hip_bfloat16*)(ws + 4 * SZ_W + 2 * SZ_QK);
    __hip_bfloat16* ctc = (__hip_bfloat16*)(ws + 4 * SZ_W + 2 * SZ_QK + SZ_V);

    // Weight transposes
    {
        dim3 tg(R_N / 32, H_N / 32, 3);
        transpose3_kernel<<<tg, 256, 0, stream>>>(Wq, Wk, Wv, WqT, WkT, WvT, R_N, H_N);
        dim3 to(H_N / 32, R_N / 32);
        transpose_kernel<<<to, 256, 0, stream>>>(Wo, WoT, H_N, R_N);
    }

    // zero V^T pad columns once (Vc reused across chunks; proj never touches them)
    {
        int total = C * NH_N * HD_N * (SP_N - S_N);
        padv_kernel<<<(total + 255) / 256, 256, 0, stream>>>(Vc, total);
    }

    for (int c0 = 0; c0 < B_N; c0 += C) {
        const int Mc = C * S_N;
        const size_t xoff = (size_t)c0 * S_N * R_N;

        // bf16 copies of the low-rank activations, aliased onto ctc (live only
        // until attn overwrites ctc -- proj finishes reading them before that).
        __hip_bfloat16* Xq = ctc;
        __hip_bfloat16* Xk = ctc + (size_t)Mc * R_N;
        __hip_bfloat16* Xv = ctc + 2 * (size_t)Mc * R_N;
        {
            int n8 = Mc * R_N / 8;
            dim3 cg((n8 + 255) / 256, 3);
            cvtx_kernel<<<cg, 256, 0, stream>>>(q_low + xoff, k_low + xoff, v_low + xoff,
                                                Xq, Xk, Xv, n8);
        }

        dim3 pg((Mc + 127) / 128, H_N / 128, 3);
        qkvproj_kernel<<<pg, 256, 0, stream>>>(Xq, Xk, Xv, WqT, WkT, WvT,
                                               bq, bk, bv, Qc, Kc, Vc, Mc, QSCALE);

        dim3 ag(C * NH_N, (S_N + 127) / 128);
        attn_kernel<<<ag, 256, 0, stream>>>(Qc, Kc, Vc, ctc);

        dim3 dg((Mc + 63) / 64, R_N / 128);
        dproj_kernel<<<dg, 256, 0, stream>>>(ctc, WoT, out + xoff, Mc);
    }
}

// Round 7
// 532.905 us; speedup vs baseline: 1.2073x; 1.0502x over previous
//
#include <hip/hip_runtime.h>
#include <hip/hip_bf16.h>
#include <math.h>

using short8   = __attribute__((ext_vector_type(8))) short;
using floatx4  = __attribute__((ext_vector_type(4))) float;
using floatx16 = __attribute__((ext_vector_type(16))) float;

#define B_N  32
#define S_N  1026
#define R_N  256
#define H_N  1024
#define NH_N 16
#define HD_N 64
#define SP_N 1088          // padded S for V^T rows: 17 * 64, pad cols zeroed once
#define KTILES 17          // SP_N / 64
#define CS_LD 136          // C-tile LDS leading dim (keeps 16B row alignment)

__device__ __forceinline__ float bf2f(__hip_bfloat16 x) { return __bfloat162float(x); }
__device__ __forceinline__ __hip_bfloat16 f2bf(float x) { return __float2bfloat16(x); }

__device__ __forceinline__ float fast_exp2(float x) {
#if __has_builtin(__builtin_amdgcn_exp2f)
    return __builtin_amdgcn_exp2f(x);
#else
    return exp2f(x);
#endif
}

// pack two f32 -> one u32 of two bf16 (RNE), single instruction
__device__ __forceinline__ unsigned cvtpk(float lo, float hi_) {
    unsigned r;
    asm("v_cvt_pk_bf16_f32 %0, %1, %2" : "=v"(r) : "v"(lo), "v"(hi_));
    return r;
}

// async global->LDS, 16B per lane; LDS dest = uniform base + lane*16
__device__ __forceinline__ void gl_lds16(const void* g, void* l) {
    __builtin_amdgcn_global_load_lds(
        (const __attribute__((address_space(1))) unsigned int*)g,
        (__attribute__((address_space(3))) unsigned int*)l, 16, 0, 0);
}

// m157 XCD swizzle (bijective iff nwg % 8 == 0, else identity): contiguous
// chunk of tile space per XCD.
__device__ __forceinline__ int xcd_swz(int o, int nwg) {
    return ((nwg & 7) == 0) ? ((o & 7) * (nwg >> 3) + (o >> 3)) : o;
}

// convert 8 fp32 (two float4) -> short8 of bf16
__device__ __forceinline__ short8 cvt8(const float* __restrict__ p) {
    floatx4 a = *(const floatx4*)p;
    floatx4 b = *(const floatx4*)(p + 4);
    short8 o;
    __hip_bfloat16* op = (__hip_bfloat16*)&o;
    op[0] = f2bf(a[0]); op[1] = f2bf(a[1]); op[2] = f2bf(a[2]); op[3] = f2bf(a[3]);
    op[4] = f2bf(b[0]); op[5] = f2bf(b[1]); op[6] = f2bf(b[2]); op[7] = f2bf(b[3]);
    return o;
}

// ---------------- LDS-tiled transpose + downcast for Wq/Wk/Wv (one launch, z-select) ---
__global__ __launch_bounds__(256) void transpose3_kernel(
    const float* __restrict__ a, const float* __restrict__ b, const float* __restrict__ c,
    __hip_bfloat16* __restrict__ oa, __hip_bfloat16* __restrict__ ob,
    __hip_bfloat16* __restrict__ oc, int K, int N) {
    __shared__ __hip_bfloat16 t[32][33];
    const float* in = (blockIdx.z == 0) ? a : (blockIdx.z == 1) ? b : c;
    __hip_bfloat16* out = (blockIdx.z == 0) ? oa : (blockIdx.z == 1) ? ob : oc;
    const int k0 = blockIdx.x * 32, n0 = blockIdx.y * 32;
    const int tx = threadIdx.x & 31, ty = threadIdx.x >> 5;   // 32 x 8
#pragma unroll
    for (int j = 0; j < 32; j += 8)
        t[ty + j][tx] = f2bf(in[(size_t)(k0 + ty + j) * N + n0 + tx]);
    __syncthreads();
#pragma unroll
    for (int j = 0; j < 32; j += 8)
        out[(size_t)(n0 + ty + j) * K + k0 + tx] = t[tx][ty + j];
}

__global__ __launch_bounds__(256) void transpose_kernel(const float* __restrict__ in,
                                                        __hip_bfloat16* __restrict__ out,
                                                        int K, int N) {
    __shared__ __hip_bfloat16 t[32][33];
    const int k0 = blockIdx.x * 32, n0 = blockIdx.y * 32;
    const int tx = threadIdx.x & 31, ty = threadIdx.x >> 5;
#pragma unroll
    for (int j = 0; j < 32; j += 8)
        t[ty + j][tx] = f2bf(in[(size_t)(k0 + ty + j) * N + n0 + tx]);
    __syncthreads();
#pragma unroll
    for (int j = 0; j < 32; j += 8)
        out[(size_t)(n0 + ty + j) * K + k0 + tx] = t[tx][ty + j];
}

// ---------------- fused fp32 -> bf16 convert for q/k/v_low (one launch) ----------------
__global__ __launch_bounds__(256) void cvtx_kernel(
    const float* __restrict__ q, const float* __restrict__ k, const float* __restrict__ v,
    __hip_bfloat16* __restrict__ oq, __hip_bfloat16* __restrict__ ok,
    __hip_bfloat16* __restrict__ ov, int n8) {
    int idx = blockIdx.x * 256 + threadIdx.x;
    if (idx >= n8) return;
    const float* s = (blockIdx.y == 0) ? q : (blockIdx.y == 1) ? k : v;
    __hip_bfloat16* d = (blockIdx.y == 0) ? oq : (blockIdx.y == 1) ? ok : ov;
    *(short8*)(d + (size_t)idx * 8) = cvt8(s + (size_t)idx * 8);
}

// ---------------- zero the V^T pad columns [S_N, SP_N) once per launch ----------------
__global__ void padv_kernel(__hip_bfloat16* __restrict__ Vt, int total) {
    int idx = blockIdx.x * 256 + threadIdx.x;
    if (idx < total) {
        int p  = idx % (SP_N - S_N);
        int rd = idx / (SP_N - S_N);          // row index over C*NH*HD d-rows
        Vt[(size_t)rd * SP_N + S_N + p] = f2bf(0.f);
    }
}

// ---------------- fused QKV up-projection, 128x128 tile, BK=64, XOR-swizzled LDS -------
// Epilogue repacks the C tile through LDS (aliased over As/Bs) for WIDE stores:
// mode 0 (Q,K): 8 x short8 per thread.  mode 1 (V): b32 stores (s parity = even).
__global__ __launch_bounds__(256) void qkvproj_kernel(
    const __hip_bfloat16* __restrict__ Xq, const __hip_bfloat16* __restrict__ Xk,
    const __hip_bfloat16* __restrict__ Xv,
    const __hip_bfloat16* __restrict__ WqT, const __hip_bfloat16* __restrict__ WkT,
    const __hip_bfloat16* __restrict__ WvT,
    const float* __restrict__ bq, const float* __restrict__ bk,
    const float* __restrict__ bv,
    __hip_bfloat16* __restrict__ Qc, __hip_bfloat16* __restrict__ Kc,
    __hip_bfloat16* __restrict__ Vc, int Mc, float qscale) {
    __shared__ char smem[65536];
    typedef __hip_bfloat16 (*AB_t)[128][64];
    AB_t As = (AB_t)smem;                    // [2][128][64], chunk^=(row&7)
    AB_t Bs = (AB_t)(smem + 32768);
    __hip_bfloat16* Cs = (__hip_bfloat16*)smem;   // [128][CS_LD], aliased after K-loop

    // ---- XCD-swizzled tile decode: y (n-tile, 8) fastest, then x (m-tile), then z ----
    const int nx = gridDim.x;                  // m-tiles
    const int nwg = nx * 8 * 3;
    const int o = blockIdx.x + nx * (blockIdx.y + 8 * blockIdx.z);
    const int tlin = xcd_swz(o, nwg);
    const int ty = tlin & 7;
    const int rest = tlin >> 3;
    const int tx = rest % nx, tz = rest / nx;

    const __hip_bfloat16* X  = (tz == 0) ? Xq  : (tz == 1) ? Xk  : Xv;
    const __hip_bfloat16* WT = (tz == 0) ? WqT : (tz == 1) ? WkT : WvT;
    const float* bias        = (tz == 0) ? bq  : (tz == 1) ? bk  : bv;
    __hip_bfloat16* out      = (tz == 0) ? Qc  : (tz == 1) ? Kc  : Vc;
    const float oscale = (tz == 0) ? qscale : 1.0f;
    const int mode = (tz == 2);

    const int tid  = threadIdx.x;
    const int wave = tid >> 6, lane = tid & 63;
    const int quad = lane >> 4, l16 = lane & 15;
    const int tm = tx * 128, tn = ty * 128;
    const int mw = (wave >> 1) * 64, nw = (wave & 1) * 64;
    const int lr = lane >> 3;                  // row within 8-row slab
    const int sc = (lane & 7) ^ lr;            // pre-swizzled source chunk

    floatx4 acc[4][4] = {};

    auto stage = [&](int bb, int kk) {
#pragma unroll
        for (int s8 = 0; s8 < 4; ++s8) {
            int row = wave * 32 + s8 * 8;      // slab base (wave-uniform)
            int gm = tm + row + lr; if (gm >= Mc) gm = Mc - 1;
            gl_lds16(X + (size_t)gm * R_N + kk + sc * 8, &As[bb][row][0]);
            gl_lds16(WT + (size_t)(tn + row + lr) * R_N + kk + sc * 8, &Bs[bb][row][0]);
        }
    };

    stage(0, 0);
    __syncthreads();                           // drains vmcnt(0)

    for (int t = 0; t < R_N / 64; ++t) {
        const int bb = t & 1;
        if (t + 1 < R_N / 64) stage(bb ^ 1, (t + 1) * 64);   // prefetch next K-tile
        short8 af[4][2], bfr[4][2];
#pragma unroll
        for (int mb = 0; mb < 4; ++mb) {
            int row = mw + mb * 16 + l16;
            const char* rp = (const char*)&As[bb][row][0];
#pragma unroll
            for (int k2 = 0; k2 < 2; ++k2)
                af[mb][k2] = *(const short8*)(rp + ((((k2 * 4 + quad)) ^ (row & 7)) << 4));
        }
#pragma unroll
        for (int nb = 0; nb < 4; ++nb) {
            int row = nw + nb * 16 + l16;
            const char* rp = (const char*)&Bs[bb][row][0];
#pragma unroll
            for (int k2 = 0; k2 < 2; ++k2)
                bfr[nb][k2] = *(const short8*)(rp + ((((k2 * 4 + quad)) ^ (row & 7)) << 4));
        }
        if (mode == 0) {
#pragma unroll
            for (int mb = 0; mb < 4; ++mb)
#pragma unroll
                for (int nb = 0; nb < 4; ++nb) {
                    acc[mb][nb] = __builtin_amdgcn_mfma_f32_16x16x32_bf16(af[mb][0], bfr[nb][0], acc[mb][nb], 0, 0, 0);
                    acc[mb][nb] = __builtin_amdgcn_mfma_f32_16x16x32_bf16(af[mb][1], bfr[nb][1], acc[mb][nb], 0, 0, 0);
                }
        } else {   // transposed product: C rows = n (d), cols = m (s)
#pragma unroll
            for (int mb = 0; mb < 4; ++mb)
#pragma unroll
                for (int nb = 0; nb < 4; ++nb) {
                    acc[mb][nb] = __builtin_amdgcn_mfma_f32_16x16x32_bf16(bfr[nb][0], af[mb][0], acc[mb][nb], 0, 0, 0);
                    acc[mb][nb] = __builtin_amdgcn_mfma_f32_16x16x32_bf16(bfr[nb][1], af[mb][1], acc[mb][nb], 0, 0, 0);
                }
        }
        __syncthreads();   // prefetch landed + all waves done with buf bb
    }

    // ---- epilogue: repack C tile through LDS, then wide stores ----
    if (mode == 0) {
#pragma unroll
        for (int mb = 0; mb < 4; ++mb)
#pragma unroll
            for (int nb = 0; nb < 4; ++nb) {
                int j = nw + nb * 16 + l16;
                float bv_ = bias[tn + j];
#pragma unroll
                for (int r = 0; r < 4; ++r) {
                    int i = mw + mb * 16 + quad * 4 + r;
                    Cs[i * CS_LD + j] = f2bf(oscale * (acc[mb][nb][r] + bv_));
                }
            }
    } else {
#pragma unroll
        for (int mb = 0; mb < 4; ++mb)
#pragma unroll
            for (int nb = 0; nb < 4; ++nb)
#pragma unroll
                for (int r = 0; r < 4; ++r) {
                    int i = nw + nb * 16 + quad * 4 + r;   // d-row
                    int j = mw + mb * 16 + l16;            // m-col
                    Cs[i * CS_LD + j] = f2bf(acc[mb][nb][r] + bias[tn + i]);
                }
    }
    __syncthreads();

    const int i = tid >> 1, half = tid & 1;
    if (mode == 0) {
        int m = tm + i;
        if (m < Mc) {
            int bl = m / S_N, s = m - bl * S_N;
            int h = (tn >> 6) + half;
            size_t ob = ((size_t)((bl * NH_N + h) * S_N + s)) * HD_N;
            const __hip_bfloat16* src = Cs + i * CS_LD + half * 64;
#pragma unroll
            for (int j = 0; j < 8; ++j)
                *(short8*)(out + ob + j * 8) = *(const short8*)(src + j * 8);
        }
    } else {
        int n = tn + i;                        // d-row index
        int h = n >> 6, d = n & 63;
        const __hip_bfloat16* src = Cs + i * CS_LD + half * 64;
#pragma unroll
        for (int j = 0; j < 8; ++j) {
            int m0 = tm + half * 64 + j * 8;
            if (m0 >= Mc) continue;            // Mc % 8 == 0 -> whole group out
            short8 w = *(const short8*)(src + j * 8);
            int bl = m0 / S_N, s0 = m0 - bl * S_N;
            size_t ob = ((size_t)((bl * NH_N + h) * HD_N + d)) * SP_N;
            if (s0 + 8 <= S_N) {               // same bl: 4 x b32 (s0 even -> 4B aligned)
                const unsigned* wp = (const unsigned*)&w;
#pragma unroll
                for (int k = 0; k < 4; ++k)
                    *(unsigned*)(out + ob + s0 + 2 * k) = wp[k];
            } else {                           // straddles bl boundary: elementwise
                const __hip_bfloat16* we = (const __hip_bfloat16*)&w;
#pragma unroll
                for (int e = 0; e < 8; ++e) {
                    int m = m0 + e;
                    int bl2 = m / S_N, s2 = m - bl2 * S_N;
                    out[((size_t)((bl2 * NH_N + h) * HD_N + d)) * SP_N + s2] = we[e];
                }
            }
        }
    }
}

// ---------------- flash attention: swapped QK^T (32x32x16), in-register softmax --------
__global__ __launch_bounds__(256, 3) void attn_kernel(
    const __hip_bfloat16* __restrict__ Qh,  // [C*NH, S, HD]  (pre-scaled by log2e/8)
    const __hip_bfloat16* __restrict__ Kh,  // [C*NH, S, HD]
    const __hip_bfloat16* __restrict__ Vt,  // [C*NH, HD, SP] (pad cols zeroed)
    __hip_bfloat16* __restrict__ ctx) {     // [C, S, NH*HD]
    __shared__ __hip_bfloat16 Kl[2][64][64];   // [buf][key][d], chunk^=(key&7)
    __shared__ __hip_bfloat16 Vl[2][64][64];   // [buf][d][key], chunk^=(d&7)

    // XCD-swizzled decode: q-tile (gridDim.y) fastest so a head's q-tiles share L2
    const int ny = gridDim.y;
    const int nwg = gridDim.x * ny;
    const int o = blockIdx.x + gridDim.x * blockIdx.y;
    const int tlin = xcd_swz(o, nwg);
    const int bh = tlin / ny;
    const int q0 = (tlin % ny) * 128;

    const int tid = threadIdx.x;
    const int wave = tid >> 6, lane = tid & 63;
    const int c = lane & 31, hi = lane >> 5, c7 = c & 7;
    const size_t base  = (size_t)bh * S_N * HD_N;
    const size_t vbase = (size_t)bh * HD_N * SP_N;

    // staging lane constants: lane covers (row lr, chunk lane&7) of an 8-row slab
    const int lr = lane >> 3;          // 0..7
    const int sc = (lane & 7) ^ lr;    // pre-swizzled source chunk ((row&7)==lr)

    // ---- Q B-frags in registers: lane holds Q[q0+wave*32+c][16*i + 8*hi + j] ----
    short8 qf[4];
    {
        int qrow = q0 + wave * 32 + c;
        if (qrow > S_N - 1) qrow = S_N - 1;            // dup row; outputs guarded
        const __hip_bfloat16* qp = Qh + base + (size_t)qrow * HD_N + hi * 8;
#pragma unroll
        for (int i = 0; i < 4; ++i) qf[i] = *(const short8*)(qp + 16 * i);
    }

    floatx16 oacc[2] = {};   // O[q (regs)][d = 32*db + c]
    float lsum = 0.f;        // partial row-sum for q=c (this hi-half's keys)

    auto stage = [&](int bb, int kt) {
#pragma unroll
        for (int j = 0; j < 2; ++j) {
            int r = 16 * wave + 8 * j + lr;            // tile row 0..63
            int krow = kt + r;
            if (krow > S_N - 1) krow = S_N - 1;        // dup; masked by key index
            gl_lds16(Kh + base + (size_t)krow * HD_N + sc * 8,
                     &Kl[bb][16 * wave + 8 * j][0]);
            gl_lds16(Vt + vbase + (size_t)r * SP_N + kt + sc * 8,
                     &Vl[bb][16 * wave + 8 * j][0]);
        }
    };

    stage(0, 0);
    __syncthreads();                                    // implies vmcnt(0) drain

    int bb = 0;
    for (int t = 0; t < KTILES; ++t) {
        const int kt = t * 64;
        if (t + 1 < KTILES) stage(bb ^ 1, kt + 64);     // prefetch next tile
        const bool last = (kt + 64 > S_N);

        short8 pa[2][2];                                // P A-frags [sub][16-key step]
#pragma unroll
        for (int sub = 0; sub < 2; ++sub) {
            // S^T = K_tile(32) x Q^T: lane col = q (=c), regs = key rows
            floatx16 sacc = {};
            __builtin_amdgcn_s_setprio(1);
#pragma unroll
            for (int i = 0; i < 4; ++i) {
                short8 kf = *(const short8*)&Kl[bb][32 * sub + c][(((2 * i + hi) ^ c7) << 3)];
                sacc = __builtin_amdgcn_mfma_f32_32x32x16_bf16(kf, qf[i], sacc, 0, 0, 0);
            }
            __builtin_amdgcn_s_setprio(0);
            float ps[16];
            if (!last) {
#pragma unroll
                for (int r = 0; r < 16; ++r) ps[r] = fast_exp2(sacc[r]);
            } else {
#pragma unroll
                for (int r = 0; r < 16; ++r) {
                    int key = kt + 32 * sub + (r & 3) + 8 * (r >> 2) + 4 * hi;
                    ps[r] = (key < S_N) ? fast_exp2(sacc[r]) : 0.f;
                }
            }
#pragma unroll
            for (int r = 0; r < 16; ++r) lsum += ps[r];
            // in-register repack: reg r holds key (r&3)+8*(r>>2)+4*hi; PV A-frag
            // needs keys 8*hi+j per 16-key step -> pair-pack + lane<->lane+32 swap
#pragma unroll
            for (int step = 0; step < 2; ++step) {
                unsigned w0 = cvtpk(ps[8 * step + 0], ps[8 * step + 1]);
                unsigned w1 = cvtpk(ps[8 * step + 2], ps[8 * step + 3]);
                unsigned w2 = cvtpk(ps[8 * step + 4], ps[8 * step + 5]);
                unsigned w3 = cvtpk(ps[8 * step + 6], ps[8 * step + 7]);
                asm("v_permlane32_swap_b32 %0, %1" : "+v"(w0), "+v"(w2));
                asm("v_permlane32_swap_b32 %0, %1" : "+v"(w1), "+v"(w3));
                union { unsigned u[4]; short8 s; } fu;
                fu.u[0] = w0; fu.u[1] = w1; fu.u[2] = w2; fu.u[3] = w3;
                pa[sub][step] = fu.s;
            }
        }

        // O += P @ V  (B-frag: V[key][d], col = d = 32*db + c)
        __builtin_amdgcn_s_setprio(1);
#pragma unroll
        for (int db = 0; db < 2; ++db)
#pragma unroll
            for (int sub = 0; sub < 2; ++sub)
#pragma unroll
                for (int step = 0; step < 2; ++step) {
                    short8 vf = *(const short8*)
                        &Vl[bb][32 * db + c][((((sub * 2 + step) * 2 + hi) ^ c7) << 3)];
                    oacc[db] = __builtin_amdgcn_mfma_f32_32x32x16_bf16(pa[sub][step], vf, oacc[db], 0, 0, 0);
                }
        __builtin_amdgcn_s_setprio(0);

        __syncthreads();    // prefetch landed (vmcnt0) + all waves done with buf bb
        bb ^= 1;
    }

    // combine the two hi-halves' partial sums; reciprocal once per q-row
    lsum += __shfl_xor(lsum, 32);
    float rs = 1.0f / lsum;

    const int bl = bh / NH_N, h = bh - bl * NH_N;
    const int srow0 = q0 + wave * 32;
#pragma unroll
    for (int r = 0; r < 16; ++r) {
        int q = (r & 3) + 8 * (r >> 2) + 4 * hi;       // O row of reg r
        float rr = __shfl(rs, q, 32);                  // rs lives at lane c==q (both halves)
        int s = srow0 + q;
        if (s < S_N) {
            size_t o2 = ((size_t)(bl * S_N + s)) * H_N + h * HD_N + c;
            ctx[o2]      = f2bf(oacc[0][r] * rr);
            ctx[o2 + 32] = f2bf(oacc[1][r] * rr);
        }
    }
}

// ---------------- down-projection, 64x128 tile, BK=64, XOR-swizzled LDS + gelu ---------
// Epilogue repacks through LDS: 8 x float4 stores per thread (was 32 scalar).
__global__ __launch_bounds__(256) void dproj_kernel(
    const __hip_bfloat16* __restrict__ X,    // ctx [Mc, H_N] bf16
    const __hip_bfloat16* __restrict__ WT,   // WoT [R_N, H_N] bf16
    float* __restrict__ out,                 // [Mc, R_N] fp32
    int Mc) {
    __shared__ char smem[49152];
    typedef __hip_bfloat16 (*A_t)[64][64];
    typedef __hip_bfloat16 (*B_t)[128][64];
    A_t As = (A_t)smem;                      // [2][64][64]   16 KB
    B_t Bs = (B_t)(smem + 16384);            // [2][128][64]  32 KB
    float* Csf = (float*)smem;               // [64][CS_LD] f32, aliased after K-loop

    // plain decode (grid 514 blocks, not XCD-divisible -- skip swizzle)
    const int tx = blockIdx.x, ty = blockIdx.y;

    const int tid  = threadIdx.x;
    const int wave = tid >> 6, lane = tid & 63;
    const int quad = lane >> 4, l16 = lane & 15;
    const int tm = tx * 64, tn = ty * 128;
    const int mw = (wave >> 1) * 32, nw = (wave & 1) * 64;
    const int lr = lane >> 3;
    const int sc = (lane & 7) ^ lr;

    floatx4 acc[2][4] = {};

    auto stage = [&](int bb, int kk) {
#pragma unroll
        for (int s8 = 0; s8 < 2; ++s8) {
            int row = wave * 16 + s8 * 8;
            int gm = tm + row + lr; if (gm >= Mc) gm = Mc - 1;
            gl_lds16(X + (size_t)gm * H_N + kk + sc * 8, &As[bb][row][0]);
        }
#pragma unroll
        for (int s8 = 0; s8 < 4; ++s8) {
            int row = wave * 32 + s8 * 8;
            gl_lds16(WT + (size_t)(tn + row + lr) * H_N + kk + sc * 8, &Bs[bb][row][0]);
        }
    };

    stage(0, 0);
    __syncthreads();

    for (int t = 0; t < H_N / 64; ++t) {
        const int bb = t & 1;
        if (t + 1 < H_N / 64) stage(bb ^ 1, (t + 1) * 64);
        short8 af[2][2], bfr[4][2];
#pragma unroll
        for (int mb = 0; mb < 2; ++mb) {
            int row = mw + mb * 16 + l16;
            const char* rp = (const char*)&As[bb][row][0];
#pragma unroll
            for (int k2 = 0; k2 < 2; ++k2)
                af[mb][k2] = *(const short8*)(rp + ((((k2 * 4 + quad)) ^ (row & 7)) << 4));
        }
#pragma unroll
        for (int nb = 0; nb < 4; ++nb) {
            int row = nw + nb * 16 + l16;
            const char* rp = (const char*)&Bs[bb][row][0];
#pragma unroll
            for (int k2 = 0; k2 < 2; ++k2)
                bfr[nb][k2] = *(const short8*)(rp + ((((k2 * 4 + quad)) ^ (row & 7)) << 4));
        }
#pragma unroll
        for (int mb = 0; mb < 2; ++mb)
#pragma unroll
            for (int nb = 0; nb < 4; ++nb) {
                acc[mb][nb] = __builtin_amdgcn_mfma_f32_16x16x32_bf16(af[mb][0], bfr[nb][0], acc[mb][nb], 0, 0, 0);
                acc[mb][nb] = __builtin_amdgcn_mfma_f32_16x16x32_bf16(af[mb][1], bfr[nb][1], acc[mb][nb], 0, 0, 0);
            }
        __syncthreads();
    }

    // ---- epilogue: gelu -> LDS repack -> float4 stores ----
#pragma unroll
    for (int mb = 0; mb < 2; ++mb)
#pragma unroll
        for (int nb = 0; nb < 4; ++nb)
#pragma unroll
            for (int r = 0; r < 4; ++r) {
                int i = mw + mb * 16 + quad * 4 + r;   // 0..63
                int j = nw + nb * 16 + l16;            // 0..127
                float x = acc[mb][nb][r];
                Csf[i * CS_LD + j] = 0.5f * x * (1.0f + erff(x * 0.70710678118654752f));
            }
    __syncthreads();

    {
        const int i = tid >> 2, q32 = tid & 3;
        int m = tm + i;
        if (m < Mc) {
            const float* src = Csf + i * CS_LD + q32 * 32;
            float* dst = out + (size_t)m * R_N + tn + q32 * 32;
#pragma unroll
            for (int jj = 0; jj < 8; ++jj)
                *(floatx4*)(dst + jj * 4) = *(const floatx4*)(src + jj * 4);
        }
    }
}

extern "C" void kernel_launch(void* const* d_in, const int* in_sizes, int n_in,
                              void* d_out, int out_size, void* d_ws, size_t ws_size,
                              hipStream_t stream) {
    const float* q_low = (const float*)d_in[0];
    const float* k_low = (const float*)d_in[1];
    const float* v_low = (const float*)d_in[2];
    const float* Wq    = (const float*)d_in[3];
    const float* bq    = (const float*)d_in[4];
    const float* Wk    = (const float*)d_in[5];
    const float* bk    = (const float*)d_in[6];
    const float* Wv    = (const float*)d_in[7];
    const float* bv    = (const float*)d_in[8];
    const float* Wo    = (const float*)d_in[9];
    float* out = (float*)d_out;
    (void)in_sizes; (void)n_in; (void)out_size;

    const float QSCALE = 0.125f * 1.44269504088896f;   // log2(e)/sqrt(HD)
    const size_t SZ_W = (size_t)H_N * R_N * 2;

    int C = 32;
    while (C > 1) {
        size_t qk = (size_t)C * NH_N * S_N * HD_N * 2;
        size_t vv = (size_t)C * NH_N * HD_N * SP_N * 2;
        size_t cx = (size_t)C * S_N * H_N * 2;
        if (4 * SZ_W + 2 * qk + vv + cx <= ws_size) break;
        C >>= 1;
    }

    char* ws = (char*)d_ws;
    const size_t SZ_QK = (size_t)C * NH_N * S_N * HD_N * 2;
    const size_t SZ_V  = (size_t)C * NH_N * HD_N * SP_N * 2;
    __hip_bfloat16* WqT = (__hip_bfloat16*)(ws);
    __hip_bfloat16* WkT = (__hip_bfloat16*)(ws + SZ_W);
    __hip_bfloat16* WvT = (__hip_bfloat16*)(ws + 2 * SZ_W);
    __hip_bfloat16* WoT = (__hip_bfloat16*)(ws + 3 * SZ_W);
    __hip_bfloat16* Qc  = (__hip_bfloat16*)(ws + 4 * SZ_W);
    __hip_bfloat16* Kc  = (__hip_bfloat16*)(ws + 4 * SZ_W + SZ_QK);
    __hip_bfloat16* Vc  = (__hip_bfloat16*)(ws + 4 * SZ_W + 2 * SZ_QK);
    __hip_bfloat16* ctc = (__hip_bfloat16*)(ws + 4 * SZ_W + 2 * SZ_QK + SZ_V);

    // Weight transposes
    {
        dim3 tg(R_N / 32, H_N / 32, 3);
        transpose3_kernel<<<tg, 256, 0, stream>>>(Wq, Wk, Wv, WqT, WkT, WvT, R_N, H_N);
        dim3 to(H_N / 32, R_N / 32);
        transpose_kernel<<<to, 256, 0, stream>>>(Wo, WoT, H_N, R_N);
    }

    // zero V^T pad columns once (Vc reused across chunks; proj never touches them)
    {
        int total = C * NH_N * HD_N * (SP_N - S_N);
        padv_kernel<<<(total + 255) / 256, 256, 0, stream>>>(Vc, total);
    }

    for (int c0 = 0; c0 < B_N; c0 += C) {
        const int Mc = C * S_N;
        const size_t xoff = (size_t)c0 * S_N * R_N;

        // bf16 copies of the low-rank activations, aliased onto ctc (live only
        // until attn overwrites ctc -- proj finishes reading them before that).
        __hip_bfloat16* Xq = ctc;
        __hip_bfloat16* Xk = ctc + (size_t)Mc * R_N;
        __hip_bfloat16* Xv = ctc + 2 * (size_t)Mc * R_N;
        {
            int n8 = Mc * R_N / 8;
            dim3 cg((n8 + 255) / 256, 3);
            cvtx_kernel<<<cg, 256, 0, stream>>>(q_low + xoff, k_low + xoff, v_low + xoff,
                                                Xq, Xk, Xv, n8);
        }

        dim3 pg((Mc + 127) / 128, H_N / 128, 3);
        qkvproj_kernel<<<pg, 256, 0, stream>>>(Xq, Xk, Xv, WqT, WkT, WvT,
                                               bq, bk, bv, Qc, Kc, Vc, Mc, QSCALE);

        dim3 ag(C * NH_N, (S_N + 127) / 128);
        attn_kernel<<<ag, 256, 0, stream>>>(Qc, Kc, Vc, ctc);

        dim3 dg((Mc + 63) / 64, R_N / 128);
        dproj_kernel<<<dg, 256, 0, stream>>>(ctc, WoT, out + xoff, Mc);
    }
}

// Round 8
// 518.123 us; speedup vs baseline: 1.2417x; 1.0285x over previous
//
#include <hip/hip_runtime.h>
#include <hip/hip_bf16.h>
#include <math.h>

using short8   = __attribute__((ext_vector_type(8))) short;
using floatx4  = __attribute__((ext_vector_type(4))) float;
using floatx16 = __attribute__((ext_vector_type(16))) float;

#define B_N  32
#define S_N  1026
#define R_N  256
#define H_N  1024
#define NH_N 16
#define HD_N 64
#define SP_N 1088          // padded S for V^T rows: 17 * 64, pad cols zeroed once
#define KTILES 17          // SP_N / 64
#define CS_LD 136          // C-tile LDS leading dim (keeps 16B row alignment)

__device__ __forceinline__ float bf2f(__hip_bfloat16 x) { return __bfloat162float(x); }
__device__ __forceinline__ __hip_bfloat16 f2bf(float x) { return __float2bfloat16(x); }

__device__ __forceinline__ float fast_exp2(float x) {
#if __has_builtin(__builtin_amdgcn_exp2f)
    return __builtin_amdgcn_exp2f(x);
#else
    return exp2f(x);
#endif
}

// pack two f32 -> one u32 of two bf16 (RNE), single instruction
__device__ __forceinline__ unsigned cvtpk(float lo, float hi_) {
    unsigned r;
    asm("v_cvt_pk_bf16_f32 %0, %1, %2" : "=v"(r) : "v"(lo), "v"(hi_));
    return r;
}

// async global->LDS, 16B per lane; LDS dest = uniform base + lane*16
__device__ __forceinline__ void gl_lds16(const void* g, void* l) {
    __builtin_amdgcn_global_load_lds(
        (const __attribute__((address_space(1))) unsigned int*)g,
        (__attribute__((address_space(3))) unsigned int*)l, 16, 0, 0);
}

// m157 XCD swizzle (bijective iff nwg % 8 == 0, else identity): contiguous
// chunk of tile space per XCD.
__device__ __forceinline__ int xcd_swz(int o, int nwg) {
    return ((nwg & 7) == 0) ? ((o & 7) * (nwg >> 3) + (o >> 3)) : o;
}

// convert 8 fp32 (two float4) -> short8 of bf16
__device__ __forceinline__ short8 cvt8(const float* __restrict__ p) {
    floatx4 a = *(const floatx4*)p;
    floatx4 b = *(const floatx4*)(p + 4);
    short8 o;
    __hip_bfloat16* op = (__hip_bfloat16*)&o;
    op[0] = f2bf(a[0]); op[1] = f2bf(a[1]); op[2] = f2bf(a[2]); op[3] = f2bf(a[3]);
    op[4] = f2bf(b[0]); op[5] = f2bf(b[1]); op[6] = f2bf(b[2]); op[7] = f2bf(b[3]);
    return o;
}

// ---------------- LDS-tiled transpose + downcast for Wq/Wk/Wv (one launch, z-select) ---
__global__ __launch_bounds__(256) void transpose3_kernel(
    const float* __restrict__ a, const float* __restrict__ b, const float* __restrict__ c,
    __hip_bfloat16* __restrict__ oa, __hip_bfloat16* __restrict__ ob,
    __hip_bfloat16* __restrict__ oc, int K, int N) {
    __shared__ __hip_bfloat16 t[32][33];
    const float* in = (blockIdx.z == 0) ? a : (blockIdx.z == 1) ? b : c;
    __hip_bfloat16* out = (blockIdx.z == 0) ? oa : (blockIdx.z == 1) ? ob : oc;
    const int k0 = blockIdx.x * 32, n0 = blockIdx.y * 32;
    const int tx = threadIdx.x & 31, ty = threadIdx.x >> 5;   // 32 x 8
#pragma unroll
    for (int j = 0; j < 32; j += 8)
        t[ty + j][tx] = f2bf(in[(size_t)(k0 + ty + j) * N + n0 + tx]);
    __syncthreads();
#pragma unroll
    for (int j = 0; j < 32; j += 8)
        out[(size_t)(n0 + ty + j) * K + k0 + tx] = t[tx][ty + j];
}

__global__ __launch_bounds__(256) void transpose_kernel(const float* __restrict__ in,
                                                        __hip_bfloat16* __restrict__ out,
                                                        int K, int N) {
    __shared__ __hip_bfloat16 t[32][33];
    const int k0 = blockIdx.x * 32, n0 = blockIdx.y * 32;
    const int tx = threadIdx.x & 31, ty = threadIdx.x >> 5;
#pragma unroll
    for (int j = 0; j < 32; j += 8)
        t[ty + j][tx] = f2bf(in[(size_t)(k0 + ty + j) * N + n0 + tx]);
    __syncthreads();
#pragma unroll
    for (int j = 0; j < 32; j += 8)
        out[(size_t)(n0 + ty + j) * K + k0 + tx] = t[tx][ty + j];
}

// ---------------- fused fp32 -> bf16 convert for q/k/v_low (one launch) ----------------
__global__ __launch_bounds__(256) void cvtx_kernel(
    const float* __restrict__ q, const float* __restrict__ k, const float* __restrict__ v,
    __hip_bfloat16* __restrict__ oq, __hip_bfloat16* __restrict__ ok,
    __hip_bfloat16* __restrict__ ov, int n8) {
    int idx = blockIdx.x * 256 + threadIdx.x;
    if (idx >= n8) return;
    const float* s = (blockIdx.y == 0) ? q : (blockIdx.y == 1) ? k : v;
    __hip_bfloat16* d = (blockIdx.y == 0) ? oq : (blockIdx.y == 1) ? ok : ov;
    *(short8*)(d + (size_t)idx * 8) = cvt8(s + (size_t)idx * 8);
}

// ---------------- zero the V^T pad columns [S_N, SP_N) once per launch ----------------
__global__ void padv_kernel(__hip_bfloat16* __restrict__ Vt, int total) {
    int idx = blockIdx.x * 256 + threadIdx.x;
    if (idx < total) {
        int p  = idx % (SP_N - S_N);
        int rd = idx / (SP_N - S_N);          // row index over C*NH*HD d-rows
        Vt[(size_t)rd * SP_N + S_N + p] = f2bf(0.f);
    }
}

// ---------------- fused QKV up-projection, 128x128 tile, BK=32 (m97 config) -----------
// 4 blocks/CU (35 KB LDS). Epilogue repacks C through LDS for wide stores.
__global__ __launch_bounds__(256) void qkvproj_kernel(
    const __hip_bfloat16* __restrict__ Xq, const __hip_bfloat16* __restrict__ Xk,
    const __hip_bfloat16* __restrict__ Xv,
    const __hip_bfloat16* __restrict__ WqT, const __hip_bfloat16* __restrict__ WkT,
    const __hip_bfloat16* __restrict__ WvT,
    const float* __restrict__ bq, const float* __restrict__ bk,
    const float* __restrict__ bv,
    __hip_bfloat16* __restrict__ Qc, __hip_bfloat16* __restrict__ Kc,
    __hip_bfloat16* __restrict__ Vc, int Mc, float qscale) {
    __shared__ char smem[34816];             // max(As+Bs = 32 KB, Cs = 34 KB)
    typedef __hip_bfloat16 (*AB_t)[128][32];
    AB_t As = (AB_t)smem;                    // [2][128][32], chunk^=(row&3)
    AB_t Bs = (AB_t)(smem + 16384);
    __hip_bfloat16* Cs = (__hip_bfloat16*)smem;   // [128][CS_LD], aliased after K-loop

    // ---- XCD-swizzled tile decode: y (n-tile, 8) fastest, then x (m-tile), then z ----
    const int nx = gridDim.x;                  // m-tiles
    const int nwg = nx * 8 * 3;
    const int o = blockIdx.x + nx * (blockIdx.y + 8 * blockIdx.z);
    const int tlin = xcd_swz(o, nwg);
    const int ty = tlin & 7;
    const int rest = tlin >> 3;
    const int tx = rest % nx, tz = rest / nx;

    const __hip_bfloat16* X  = (tz == 0) ? Xq  : (tz == 1) ? Xk  : Xv;
    const __hip_bfloat16* WT = (tz == 0) ? WqT : (tz == 1) ? WkT : WvT;
    const float* bias        = (tz == 0) ? bq  : (tz == 1) ? bk  : bv;
    __hip_bfloat16* out      = (tz == 0) ? Qc  : (tz == 1) ? Kc  : Vc;
    const float oscale = (tz == 0) ? qscale : 1.0f;
    const int mode = (tz == 2);

    const int tid  = threadIdx.x;
    const int wave = tid >> 6, lane = tid & 63;
    const int quad = lane >> 4, l16 = lane & 15;
    const int tm = tx * 128, tn = ty * 128;
    const int mw = (wave >> 1) * 64, nw = (wave & 1) * 64;
    const int lr = lane >> 2;                  // row within 16-row slab (0..15)
    const int sc4 = (lane & 3) ^ (lr & 3);     // pre-swizzled source chunk (16B units)

    floatx4 acc[4][4] = {};

    auto stage = [&](int bb, int kk) {
#pragma unroll
        for (int s16 = 0; s16 < 2; ++s16) {
            int row = wave * 32 + s16 * 16;    // slab base (wave-uniform)
            int gm = tm + row + lr; if (gm >= Mc) gm = Mc - 1;
            gl_lds16(X + (size_t)gm * R_N + kk + sc4 * 8, &As[bb][row][0]);
            gl_lds16(WT + (size_t)(tn + row + lr) * R_N + kk + sc4 * 8, &Bs[bb][row][0]);
        }
    };

    stage(0, 0);
    __syncthreads();                           // drains vmcnt(0)

    for (int t = 0; t < R_N / 32; ++t) {
        const int bb = t & 1;
        if (t + 1 < R_N / 32) stage(bb ^ 1, (t + 1) * 32);   // prefetch next K-tile
        short8 af[4], bfr[4];
#pragma unroll
        for (int mb = 0; mb < 4; ++mb) {
            int row = mw + mb * 16 + l16;
            af[mb] = *(const short8*)((const char*)&As[bb][row][0] + ((quad ^ (row & 3)) << 4));
        }
#pragma unroll
        for (int nb = 0; nb < 4; ++nb) {
            int row = nw + nb * 16 + l16;
            bfr[nb] = *(const short8*)((const char*)&Bs[bb][row][0] + ((quad ^ (row & 3)) << 4));
        }
        if (mode == 0) {
#pragma unroll
            for (int mb = 0; mb < 4; ++mb)
#pragma unroll
                for (int nb = 0; nb < 4; ++nb)
                    acc[mb][nb] = __builtin_amdgcn_mfma_f32_16x16x32_bf16(af[mb], bfr[nb], acc[mb][nb], 0, 0, 0);
        } else {   // transposed product: C rows = n (d), cols = m (s)
#pragma unroll
            for (int mb = 0; mb < 4; ++mb)
#pragma unroll
                for (int nb = 0; nb < 4; ++nb)
                    acc[mb][nb] = __builtin_amdgcn_mfma_f32_16x16x32_bf16(bfr[nb], af[mb], acc[mb][nb], 0, 0, 0);
        }
        __syncthreads();   // prefetch landed + all waves done with buf bb
    }

    // ---- epilogue: repack C tile through LDS, then wide stores ----
    if (mode == 0) {
#pragma unroll
        for (int mb = 0; mb < 4; ++mb)
#pragma unroll
            for (int nb = 0; nb < 4; ++nb) {
                int j = nw + nb * 16 + l16;
                float bv_ = bias[tn + j];
#pragma unroll
                for (int r = 0; r < 4; ++r) {
                    int i = mw + mb * 16 + quad * 4 + r;
                    Cs[i * CS_LD + j] = f2bf(oscale * (acc[mb][nb][r] + bv_));
                }
            }
    } else {
#pragma unroll
        for (int mb = 0; mb < 4; ++mb)
#pragma unroll
            for (int nb = 0; nb < 4; ++nb)
#pragma unroll
                for (int r = 0; r < 4; ++r) {
                    int i = nw + nb * 16 + quad * 4 + r;   // d-row
                    int j = mw + mb * 16 + l16;            // m-col
                    Cs[i * CS_LD + j] = f2bf(acc[mb][nb][r] + bias[tn + i]);
                }
    }
    __syncthreads();

    const int i = tid >> 1, half = tid & 1;
    if (mode == 0) {
        int m = tm + i;
        if (m < Mc) {
            int bl = m / S_N, s = m - bl * S_N;
            int h = (tn >> 6) + half;
            size_t ob = ((size_t)((bl * NH_N + h) * S_N + s)) * HD_N;
            const __hip_bfloat16* src = Cs + i * CS_LD + half * 64;
#pragma unroll
            for (int j = 0; j < 8; ++j)
                *(short8*)(out + ob + j * 8) = *(const short8*)(src + j * 8);
        }
    } else {
        int n = tn + i;                        // d-row index
        int h = n >> 6, d = n & 63;
        const __hip_bfloat16* src = Cs + i * CS_LD + half * 64;
#pragma unroll
        for (int j = 0; j < 8; ++j) {
            int m0 = tm + half * 64 + j * 8;
            if (m0 >= Mc) continue;            // Mc % 8 == 0 -> whole group out
            short8 w = *(const short8*)(src + j * 8);
            int bl = m0 / S_N, s0 = m0 - bl * S_N;
            size_t ob = ((size_t)((bl * NH_N + h) * HD_N + d)) * SP_N;
            if (s0 + 8 <= S_N) {               // same bl: 4 x b32 (s0 even -> 4B aligned)
                const unsigned* wp = (const unsigned*)&w;
#pragma unroll
                for (int k = 0; k < 4; ++k)
                    *(unsigned*)(out + ob + s0 + 2 * k) = wp[k];
            } else {                           // straddles bl boundary: elementwise
                const __hip_bfloat16* we = (const __hip_bfloat16*)&w;
#pragma unroll
                for (int e = 0; e < 8; ++e) {
                    int m = m0 + e;
                    int bl2 = m / S_N, s2 = m - bl2 * S_N;
                    out[((size_t)((bl2 * NH_N + h) * HD_N + d)) * SP_N + s2] = we[e];
                }
            }
        }
    }
}

// ---------------- flash attention: swapped QK^T (32x32x16), in-register softmax --------
// Row-sums computed on the MATRIX pipe (P @ ones) in the same register layout as O.
__global__ __launch_bounds__(256, 3) void attn_kernel(
    const __hip_bfloat16* __restrict__ Qh,  // [C*NH, S, HD]  (pre-scaled by log2e/8)
    const __hip_bfloat16* __restrict__ Kh,  // [C*NH, S, HD]
    const __hip_bfloat16* __restrict__ Vt,  // [C*NH, HD, SP] (pad cols zeroed)
    __hip_bfloat16* __restrict__ ctx) {     // [C, S, NH*HD]
    __shared__ __hip_bfloat16 Kl[2][64][64];   // [buf][key][d], chunk^=(key&7)
    __shared__ __hip_bfloat16 Vl[2][64][64];   // [buf][d][key], chunk^=(d&7)

    // XCD-swizzled decode: q-tile (gridDim.y) fastest so a head's q-tiles share L2
    const int ny = gridDim.y;
    const int nwg = gridDim.x * ny;
    const int o = blockIdx.x + gridDim.x * blockIdx.y;
    const int tlin = xcd_swz(o, nwg);
    const int bh = tlin / ny;
    const int q0 = (tlin % ny) * 128;

    const int tid = threadIdx.x;
    const int wave = tid >> 6, lane = tid & 63;
    const int c = lane & 31, hi = lane >> 5, c7 = c & 7;
    const size_t base  = (size_t)bh * S_N * HD_N;
    const size_t vbase = (size_t)bh * HD_N * SP_N;

    // staging lane constants: lane covers (row lr, chunk lane&7) of an 8-row slab
    const int lr = lane >> 3;          // 0..7
    const int sc = (lane & 7) ^ lr;    // pre-swizzled source chunk ((row&7)==lr)

    // all-ones B-frag (bf16 1.0) for rowsum-by-MFMA
    const short ONE = 0x3F80;
    const short8 onesb = {ONE, ONE, ONE, ONE, ONE, ONE, ONE, ONE};

    // ---- Q B-frags in registers: lane holds Q[q0+wave*32+c][16*i + 8*hi + j] ----
    short8 qf[4];
    {
        int qrow = q0 + wave * 32 + c;
        if (qrow > S_N - 1) qrow = S_N - 1;            // dup row; outputs guarded
        const __hip_bfloat16* qp = Qh + base + (size_t)qrow * HD_N + hi * 8;
#pragma unroll
        for (int i = 0; i < 4; ++i) qf[i] = *(const short8*)(qp + 16 * i);
    }

    floatx16 oacc[2] = {};   // O[q (regs)][d = 32*db + c]
    floatx16 rsacc = {};     // row sums, same reg layout as oacc

    auto stage = [&](int bb, int kt) {
#pragma unroll
        for (int j = 0; j < 2; ++j) {
            int r = 16 * wave + 8 * j + lr;            // tile row 0..63
            int krow = kt + r;
            if (krow > S_N - 1) krow = S_N - 1;        // dup; masked by key index
            gl_lds16(Kh + base + (size_t)krow * HD_N + sc * 8,
                     &Kl[bb][16 * wave + 8 * j][0]);
            gl_lds16(Vt + vbase + (size_t)r * SP_N + kt + sc * 8,
                     &Vl[bb][16 * wave + 8 * j][0]);
        }
    };

    stage(0, 0);
    __syncthreads();                                    // implies vmcnt(0) drain

    int bb = 0;
    for (int t = 0; t < KTILES; ++t) {
        const int kt = t * 64;
        if (t + 1 < KTILES) stage(bb ^ 1, kt + 64);     // prefetch next tile
        const bool last = (kt + 64 > S_N);

        short8 pa[2][2];                                // P A-frags [sub][16-key step]
#pragma unroll
        for (int sub = 0; sub < 2; ++sub) {
            // S^T = K_tile(32) x Q^T: lane col = q (=c), regs = key rows
            floatx16 sacc = {};
            __builtin_amdgcn_s_setprio(1);
#pragma unroll
            for (int i = 0; i < 4; ++i) {
                short8 kf = *(const short8*)&Kl[bb][32 * sub + c][(((2 * i + hi) ^ c7) << 3)];
                sacc = __builtin_amdgcn_mfma_f32_32x32x16_bf16(kf, qf[i], sacc, 0, 0, 0);
            }
            __builtin_amdgcn_s_setprio(0);
            float ps[16];
            if (!last) {
#pragma unroll
                for (int r = 0; r < 16; ++r) ps[r] = fast_exp2(sacc[r]);
            } else {
#pragma unroll
                for (int r = 0; r < 16; ++r) {
                    int key = kt + 32 * sub + (r & 3) + 8 * (r >> 2) + 4 * hi;
                    ps[r] = (key < S_N) ? fast_exp2(sacc[r]) : 0.f;
                }
            }
            // in-register repack: reg r holds key (r&3)+8*(r>>2)+4*hi; PV A-frag
            // needs keys 8*hi+j per 16-key step -> pair-pack + lane<->lane+32 swap
#pragma unroll
            for (int step = 0; step < 2; ++step) {
                unsigned w0 = cvtpk(ps[8 * step + 0], ps[8 * step + 1]);
                unsigned w1 = cvtpk(ps[8 * step + 2], ps[8 * step + 3]);
                unsigned w2 = cvtpk(ps[8 * step + 4], ps[8 * step + 5]);
                unsigned w3 = cvtpk(ps[8 * step + 6], ps[8 * step + 7]);
                asm("v_permlane32_swap_b32 %0, %1" : "+v"(w0), "+v"(w2));
                asm("v_permlane32_swap_b32 %0, %1" : "+v"(w1), "+v"(w3));
                union { unsigned u[4]; short8 s; } fu;
                fu.u[0] = w0; fu.u[1] = w1; fu.u[2] = w2; fu.u[3] = w3;
                pa[sub][step] = fu.s;
            }
        }

        // O += P @ V ; rowsum += P @ ones  (both on the matrix pipe)
        __builtin_amdgcn_s_setprio(1);
#pragma unroll
        for (int db = 0; db < 2; ++db)
#pragma unroll
            for (int sub = 0; sub < 2; ++sub)
#pragma unroll
                for (int step = 0; step < 2; ++step) {
                    short8 vf = *(const short8*)
                        &Vl[bb][32 * db + c][((((sub * 2 + step) * 2 + hi) ^ c7) << 3)];
                    oacc[db] = __builtin_amdgcn_mfma_f32_32x32x16_bf16(pa[sub][step], vf, oacc[db], 0, 0, 0);
                }
#pragma unroll
        for (int sub = 0; sub < 2; ++sub)
#pragma unroll
            for (int step = 0; step < 2; ++step)
                rsacc = __builtin_amdgcn_mfma_f32_32x32x16_bf16(pa[sub][step], onesb, rsacc, 0, 0, 0);
        __builtin_amdgcn_s_setprio(0);

        __syncthreads();    // prefetch landed (vmcnt0) + all waves done with buf bb
        bb ^= 1;
    }

    const int bl = bh / NH_N, h = bh - bl * NH_N;
    const int srow0 = q0 + wave * 32;
#pragma unroll
    for (int r = 0; r < 16; ++r) {
        int q = (r & 3) + 8 * (r >> 2) + 4 * hi;       // O row of reg r
        int s = srow0 + q;
        if (s < S_N) {
            float rr = 1.0f / rsacc[r];                // rowsum in matching layout
            size_t o2 = ((size_t)(bl * S_N + s)) * H_N + h * HD_N + c;
            ctx[o2]      = f2bf(oacc[0][r] * rr);
            ctx[o2 + 32] = f2bf(oacc[1][r] * rr);
        }
    }
}

// ---------------- down-projection, 64x128 tile, BK=64, XOR-swizzled LDS + gelu ---------
// 1D grid padded to x8 for the XCD swizzle; epilogue via LDS repack -> float4 stores.
__global__ __launch_bounds__(256) void dproj_kernel(
    const __hip_bfloat16* __restrict__ X,    // ctx [Mc, H_N] bf16
    const __hip_bfloat16* __restrict__ WT,   // WoT [R_N, H_N] bf16
    float* __restrict__ out,                 // [Mc, R_N] fp32
    int Mc) {
    __shared__ char smem[49152];
    typedef __hip_bfloat16 (*A_t)[64][64];
    typedef __hip_bfloat16 (*B_t)[128][64];
    A_t As = (A_t)smem;                      // [2][64][64]   16 KB
    B_t Bs = (B_t)(smem + 16384);            // [2][128][64]  32 KB
    float* Csf = (float*)smem;               // [64][CS_LD] f32, aliased after K-loop

    // XCD-swizzled 1D decode, n-tile (2) fastest; padded tiles exit
    const int nx = (Mc + 63) >> 6;
    const int tlin = xcd_swz(blockIdx.x, gridDim.x);
    if (tlin >= nx * 2) return;
    const int ty = tlin & 1, tx = tlin >> 1;

    const int tid  = threadIdx.x;
    const int wave = tid >> 6, lane = tid & 63;
    const int quad = lane >> 4, l16 = lane & 15;
    const int tm = tx * 64, tn = ty * 128;
    const int mw = (wave >> 1) * 32, nw = (wave & 1) * 64;
    const int lr = lane >> 3;
    const int sc = (lane & 7) ^ lr;

    floatx4 acc[2][4] = {};

    auto stage = [&](int bb, int kk) {
#pragma unroll
        for (int s8 = 0; s8 < 2; ++s8) {
            int row = wave * 16 + s8 * 8;
            int gm = tm + row + lr; if (gm >= Mc) gm = Mc - 1;
            gl_lds16(X + (size_t)gm * H_N + kk + sc * 8, &As[bb][row][0]);
        }
#pragma unroll
        for (int s8 = 0; s8 < 4; ++s8) {
            int row = wave * 32 + s8 * 8;
            gl_lds16(WT + (size_t)(tn + row + lr) * H_N + kk + sc * 8, &Bs[bb][row][0]);
        }
    };

    stage(0, 0);
    __syncthreads();

    for (int t = 0; t < H_N / 64; ++t) {
        const int bb = t & 1;
        if (t + 1 < H_N / 64) stage(bb ^ 1, (t + 1) * 64);
        short8 af[2][2], bfr[4][2];
#pragma unroll
        for (int mb = 0; mb < 2; ++mb) {
            int row = mw + mb * 16 + l16;
            const char* rp = (const char*)&As[bb][row][0];
#pragma unroll
            for (int k2 = 0; k2 < 2; ++k2)
                af[mb][k2] = *(const short8*)(rp + ((((k2 * 4 + quad)) ^ (row & 7)) << 4));
        }
#pragma unroll
        for (int nb = 0; nb < 4; ++nb) {
            int row = nw + nb * 16 + l16;
            const char* rp = (const char*)&Bs[bb][row][0];
#pragma unroll
            for (int k2 = 0; k2 < 2; ++k2)
                bfr[nb][k2] = *(const short8*)(rp + ((((k2 * 4 + quad)) ^ (row & 7)) << 4));
        }
#pragma unroll
        for (int mb = 0; mb < 2; ++mb)
#pragma unroll
            for (int nb = 0; nb < 4; ++nb) {
                acc[mb][nb] = __builtin_amdgcn_mfma_f32_16x16x32_bf16(af[mb][0], bfr[nb][0], acc[mb][nb], 0, 0, 0);
                acc[mb][nb] = __builtin_amdgcn_mfma_f32_16x16x32_bf16(af[mb][1], bfr[nb][1], acc[mb][nb], 0, 0, 0);
            }
        __syncthreads();
    }

    // ---- epilogue: gelu -> LDS repack -> float4 stores ----
#pragma unroll
    for (int mb = 0; mb < 2; ++mb)
#pragma unroll
        for (int nb = 0; nb < 4; ++nb)
#pragma unroll
            for (int r = 0; r < 4; ++r) {
                int i = mw + mb * 16 + quad * 4 + r;   // 0..63
                int j = nw + nb * 16 + l16;            // 0..127
                float x = acc[mb][nb][r];
                Csf[i * CS_LD + j] = 0.5f * x * (1.0f + erff(x * 0.70710678118654752f));
            }
    __syncthreads();

    {
        const int i = tid >> 2, q32 = tid & 3;
        int m = tm + i;
        if (m < Mc) {
            const float* src = Csf + i * CS_LD + q32 * 32;
            float* dst = out + (size_t)m * R_N + tn + q32 * 32;
#pragma unroll
            for (int jj = 0; jj < 8; ++jj)
                *(floatx4*)(dst + jj * 4) = *(const floatx4*)(src + jj * 4);
        }
    }
}

extern "C" void kernel_launch(void* const* d_in, const int* in_sizes, int n_in,
                              void* d_out, int out_size, void* d_ws, size_t ws_size,
                              hipStream_t stream) {
    const float* q_low = (const float*)d_in[0];
    const float* k_low = (const float*)d_in[1];
    const float* v_low = (const float*)d_in[2];
    const float* Wq    = (const float*)d_in[3];
    const float* bq    = (const float*)d_in[4];
    const float* Wk    = (const float*)d_in[5];
    const float* bk    = (const float*)d_in[6];
    const float* Wv    = (const float*)d_in[7];
    const float* bv    = (const float*)d_in[8];
    const float* Wo    = (const float*)d_in[9];
    float* out = (float*)d_out;
    (void)in_sizes; (void)n_in; (void)out_size;

    const float QSCALE = 0.125f * 1.44269504088896f;   // log2(e)/sqrt(HD)
    const size_t SZ_W = (size_t)H_N * R_N * 2;

    int C = 32;
    while (C > 1) {
        size_t qk = (size_t)C * NH_N * S_N * HD_N * 2;
        size_t vv = (size_t)C * NH_N * HD_N * SP_N * 2;
        size_t cx = (size_t)C * S_N * H_N * 2;
        if (4 * SZ_W + 2 * qk + vv + cx <= ws_size) break;
        C >>= 1;
    }

    char* ws = (char*)d_ws;
    const size_t SZ_QK = (size_t)C * NH_N * S_N * HD_N * 2;
    const size_t SZ_V  = (size_t)C * NH_N * HD_N * SP_N * 2;
    __hip_bfloat16* WqT = (__hip_bfloat16*)(ws);
    __hip_bfloat16* WkT = (__hip_bfloat16*)(ws + SZ_W);
    __hip_bfloat16* WvT = (__hip_bfloat16*)(ws + 2 * SZ_W);
    __hip_bfloat16* WoT = (__hip_bfloat16*)(ws + 3 * SZ_W);
    __hip_bfloat16* Qc  = (__hip_bfloat16*)(ws + 4 * SZ_W);
    __hip_bfloat16* Kc  = (__hip_bfloat16*)(ws + 4 * SZ_W + SZ_QK);
    __hip_bfloat16* Vc  = (__hip_bfloat16*)(ws + 4 * SZ_W + 2 * SZ_QK);
    __hip_bfloat16* ctc = (__hip_bfloat16*)(ws + 4 * SZ_W + 2 * SZ_QK + SZ_V);

    // Weight transposes
    {
        dim3 tg(R_N / 32, H_N / 32, 3);
        transpose3_kernel<<<tg, 256, 0, stream>>>(Wq, Wk, Wv, WqT, WkT, WvT, R_N, H_N);
        dim3 to(H_N / 32, R_N / 32);
        transpose_kernel<<<to, 256, 0, stream>>>(Wo, WoT, H_N, R_N);
    }

    // zero V^T pad columns once (Vc reused across chunks; proj never touches them)
    {
        int total = C * NH_N * HD_N * (SP_N - S_N);
        padv_kernel<<<(total + 255) / 256, 256, 0, stream>>>(Vc, total);
    }

    for (int c0 = 0; c0 < B_N; c0 += C) {
        const int Mc = C * S_N;
        const size_t xoff = (size_t)c0 * S_N * R_N;

        // bf16 copies of the low-rank activations, aliased onto ctc (live only
        // until attn overwrites ctc -- proj finishes reading them before that).
        __hip_bfloat16* Xq = ctc;
        __hip_bfloat16* Xk = ctc + (size_t)Mc * R_N;
        __hip_bfloat16* Xv = ctc + 2 * (size_t)Mc * R_N;
        {
            int n8 = Mc * R_N / 8;
            dim3 cg((n8 + 255) / 256, 3);
            cvtx_kernel<<<cg, 256, 0, stream>>>(q_low + xoff, k_low + xoff, v_low + xoff,
                                                Xq, Xk, Xv, n8);
        }

        dim3 pg((Mc + 127) / 128, H_N / 128, 3);
        qkvproj_kernel<<<pg, 256, 0, stream>>>(Xq, Xk, Xv, WqT, WkT, WvT,
                                               bq, bk, bv, Qc, Kc, Vc, Mc, QSCALE);

        dim3 ag(C * NH_N, (S_N + 127) / 128);
        attn_kernel<<<ag, 256, 0, stream>>>(Qc, Kc, Vc, ctc);

        // dproj: 1D grid padded to a multiple of 8 for the XCD swizzle
        int nxd = (Mc + 63) / 64;
        int dg1 = ((nxd * 2 + 7) / 8) * 8;
        dproj_kernel<<<dg1, 256, 0, stream>>>(ctc, WoT, out + xoff, Mc);
    }
}